// Round 1
// baseline (1412.413 us; speedup 1.0000x reference)
//
#include <hip/hip_runtime.h>

// Problem constants
static constexpr int NG   = 100000;
static constexpr int NC   = 2000;
static constexpr int D    = 256;
static constexpr int NE   = 1000000;
static constexpr int NOUTD= 64;

typedef __bf16 bf16x8 __attribute__((ext_vector_type(8)));
typedef float  f32x4  __attribute__((ext_vector_type(4)));

__device__ __forceinline__ unsigned short f2bf(float f) {
    unsigned u = __float_as_uint(f);
    u += 0x7fffu + ((u >> 16) & 1u);   // RNE
    return (unsigned short)(u >> 16);
}
__device__ __forceinline__ float bflo(unsigned x) { return __uint_as_float((x & 0xffffu) << 16); }
__device__ __forceinline__ float bfhi(unsigned x) { return __uint_as_float(x & 0xffff0000u); }

// ---------------- prep: f32 -> bf16 master copies + self-loop-scaled copy ----
__global__ void prep_x(const float* __restrict__ x, const float* __restrict__ w,
                       unsigned short* __restrict__ xo, unsigned short* __restrict__ vo,
                       int rows) {
    int i = blockIdx.x * blockDim.x + threadIdx.x;
    if (i >= rows * D) return;
    float xv = x[i];
    float wv = w[i >> 8];
    xo[i] = f2bf(xv);
    vo[i] = f2bf(xv * wv);
}

// ---------------- build concatenated bf16 weights [3][256][256] + bias sums --
__global__ void build_wcat(const float* __restrict__ Wa,  const float* __restrict__ Wra,
                           const float* __restrict__ Wrb, const float* __restrict__ Wb,
                           const float* __restrict__ ba,  const float* __restrict__ bb,
                           unsigned short* __restrict__ wout, float* __restrict__ bsum) {
    int i = blockIdx.x * blockDim.x + threadIdx.x;
    if (i >= D * D) return;
    wout[i]           = f2bf(Wa[i]);
    wout[D*D + i]     = f2bf(Wra[i] + Wrb[i]);
    wout[2*D*D + i]   = f2bf(Wb[i]);
    if (i < D) bsum[i] = ba[i] + bb[i];
}

// ---------------- CSR build -------------------------------------------------
__global__ void count_edges(const int* __restrict__ dst_g2c, const int* __restrict__ dst_c2g,
                            int* __restrict__ cnt_c, int* __restrict__ cnt_g) {
    int e = blockIdx.x * blockDim.x + threadIdx.x;
    if (e >= NE) return;
    atomicAdd(&cnt_c[dst_g2c[e]], 1);
    atomicAdd(&cnt_g[dst_c2g[e]], 1);
}

__global__ __launch_bounds__(1024) void scan_kernel(const int* __restrict__ cnt, int n,
                                                    int* __restrict__ rp, int* __restrict__ cur) {
    __shared__ int sd[1024];
    int tid = threadIdx.x;
    int S = (n + 1023) >> 10;
    int start = tid * S;
    int end = start + S; if (end > n) end = n;
    int sum = 0;
    for (int j = start; j < end; ++j) sum += cnt[j];
    sd[tid] = sum;
    __syncthreads();
    for (int off = 1; off < 1024; off <<= 1) {
        int t = (tid >= off) ? sd[tid - off] : 0;
        __syncthreads();
        sd[tid] += t;
        __syncthreads();
    }
    int run = sd[tid] - sum;       // exclusive prefix of this segment
    for (int j = start; j < end; ++j) { rp[j] = run; cur[j] = run; run += cnt[j]; }
    if (tid == 1023) rp[n] = sd[1023];
}

__global__ void fill_edges(const int* __restrict__ src_g2c, const int* __restrict__ dst_g2c,
                           const float* __restrict__ w_g2c,
                           const int* __restrict__ src_c2g, const int* __restrict__ dst_c2g,
                           const float* __restrict__ w_c2g,
                           int* __restrict__ cur_c, int* __restrict__ cur_g,
                           int* __restrict__ ssrc_g2c, float* __restrict__ sw_g2c,
                           int* __restrict__ ssrc_c2g, float* __restrict__ sw_c2g) {
    int e = blockIdx.x * blockDim.x + threadIdx.x;
    if (e >= NE) return;
    {
        int d = dst_g2c[e];
        int p = atomicAdd(&cur_c[d], 1);
        ssrc_g2c[p] = src_g2c[e];
        sw_g2c[p]   = w_g2c[e];
    }
    {
        int d = dst_c2g[e];
        int p = atomicAdd(&cur_g[d], 1);
        ssrc_c2g[p] = src_c2g[e];
        sw_c2g[p]   = w_c2g[e];
    }
}

// ---------------- aggregation: one wave per destination row (genes) ---------
__global__ void agg_rows_wave(const int* __restrict__ rp, const int* __restrict__ ssrc,
                              const float* __restrict__ sw, const unsigned short* __restrict__ xsrc,
                              unsigned short* __restrict__ aggout, int nrows) {
    int wave = (blockIdx.x * blockDim.x + threadIdx.x) >> 6;
    int lane = threadIdx.x & 63;
    if (wave >= nrows) return;
    int j0 = rp[wave], j1 = rp[wave + 1];
    float a0 = 0.f, a1 = 0.f, a2 = 0.f, a3 = 0.f;
    for (int j = j0; j < j1; ++j) {
        int s = ssrc[j];
        float w = sw[j];
        uint2 pk = *reinterpret_cast<const uint2*>(xsrc + (size_t)s * D + lane * 4);
        a0 += w * bflo(pk.x); a1 += w * bfhi(pk.x);
        a2 += w * bflo(pk.y); a3 += w * bfhi(pk.y);
    }
    uint2 o;
    o.x = (unsigned)f2bf(a0) | ((unsigned)f2bf(a1) << 16);
    o.y = (unsigned)f2bf(a2) | ((unsigned)f2bf(a3) << 16);
    *reinterpret_cast<uint2*>(aggout + (size_t)wave * D + lane * 4) = o;
}

// ---------------- aggregation: 8 waves per cell row, f32 atomics ------------
static constexpr int CELL_WAVES = 8;
__global__ void agg_cell_atomic(const int* __restrict__ rp, const int* __restrict__ ssrc,
                                const float* __restrict__ sw, const unsigned short* __restrict__ xg,
                                float* __restrict__ agg) {
    int gwave = (blockIdx.x * blockDim.x + threadIdx.x) >> 6;
    int lane  = threadIdx.x & 63;
    int c = gwave / CELL_WAVES, s = gwave % CELL_WAVES;
    if (c >= NC) return;
    int j0 = rp[c], j1 = rp[c + 1];
    int deg = j1 - j0;
    if (deg <= 0) return;
    int chunk = (deg + CELL_WAVES - 1) / CELL_WAVES;
    int a = j0 + s * chunk;
    int b = a + chunk; if (b > j1) b = j1;
    if (a >= b) return;
    float a0 = 0.f, a1 = 0.f, a2 = 0.f, a3 = 0.f;
    for (int j = a; j < b; ++j) {
        int src = ssrc[j];
        float w = sw[j];
        uint2 pk = *reinterpret_cast<const uint2*>(xg + (size_t)src * D + lane * 4);
        a0 += w * bflo(pk.x); a1 += w * bfhi(pk.x);
        a2 += w * bflo(pk.y); a3 += w * bfhi(pk.y);
    }
    float* o = agg + (size_t)c * D + lane * 4;
    atomicAdd(o + 0, a0); atomicAdd(o + 1, a1);
    atomicAdd(o + 2, a2); atomicAdd(o + 3, a3);
}

__global__ void f2bf_arr(const float* __restrict__ in, unsigned short* __restrict__ out, int n) {
    int i = blockIdx.x * blockDim.x + threadIdx.x;
    if (i < n) out[i] = f2bf(in[i]);
}

// ---------------- fused GEMM: relu(cat(A0,A1,A2) @ Wcat^T + bias) -----------
// Each wave: 64x64 tile via 4x4 grid of 16x16x32 bf16 MFMAs. Block: 4 waves =
// 128Mx128N; gridDim.y=2 covers N=256.
__global__ __launch_bounds__(256, 2) void gemm_fused(
        const unsigned short* __restrict__ A0,
        const unsigned short* __restrict__ A1,
        const unsigned short* __restrict__ A2,
        const unsigned short* __restrict__ W,     // [3][256][256] bf16
        const float* __restrict__ bias,           // [256]
        const float* __restrict__ wrow,           // nullable per-row scale for vout
        unsigned short* __restrict__ xout,        // [M,256] bf16
        unsigned short* __restrict__ vout,        // nullable [M,256] bf16
        int M) {
    int wave = threadIdx.x >> 6;
    int lane = threadIdx.x & 63;
    int m0 = blockIdx.x * 128 + (wave >> 1) * 64;
    int n0 = blockIdx.y * 128 + (wave & 1) * 64;
    int lm = lane & 15, lq = lane >> 4;

    f32x4 acc[4][4];
#pragma unroll
    for (int i = 0; i < 4; ++i)
#pragma unroll
        for (int j = 0; j < 4; ++j) acc[i][j] = f32x4{0.f, 0.f, 0.f, 0.f};

    int rA[4];
#pragma unroll
    for (int i = 0; i < 4; ++i) {
        int r = m0 + i * 16 + lm;
        rA[i] = r < M ? r : M - 1;
    }

    const unsigned short* Aseg[3] = {A0, A1, A2};
#pragma unroll
    for (int s = 0; s < 3; ++s) {
        const unsigned short* As = Aseg[s];
        const unsigned short* Ws = W + s * D * D;
        for (int k = 0; k < D; k += 32) {
            int ka = k + lq * 8;
            bf16x8 a[4], b[4];
#pragma unroll
            for (int i = 0; i < 4; ++i)
                a[i] = *reinterpret_cast<const bf16x8*>(As + (size_t)rA[i] * D + ka);
#pragma unroll
            for (int j = 0; j < 4; ++j)
                b[j] = *reinterpret_cast<const bf16x8*>(Ws + (size_t)(n0 + j * 16 + lm) * D + ka);
#pragma unroll
            for (int i = 0; i < 4; ++i)
#pragma unroll
                for (int j = 0; j < 4; ++j)
                    acc[i][j] = __builtin_amdgcn_mfma_f32_16x16x32_bf16(a[i], b[j], acc[i][j], 0, 0, 0);
        }
    }

    // epilogue: C[row=m0+i*16+lq*4+r][col=n0+j*16+lm]
#pragma unroll
    for (int i = 0; i < 4; ++i) {
#pragma unroll
        for (int r = 0; r < 4; ++r) {
            int rr = m0 + i * 16 + lq * 4 + r;
            if (rr >= M) continue;
            float wr = wrow ? wrow[rr] : 0.f;
#pragma unroll
            for (int j = 0; j < 4; ++j) {
                int col = n0 + j * 16 + lm;
                float v = acc[i][j][r] + bias[col];
                v = v > 0.f ? v : 0.f;
                xout[(size_t)rr * D + col] = f2bf(v);
                if (vout) vout[(size_t)rr * D + col] = f2bf(v * wr);
            }
        }
    }
}

// ---------------- final projection: out = xc2 @ Wout^T + bout (fp32) --------
__global__ void out_kernel(const unsigned short* __restrict__ xc, const float* __restrict__ Wout,
                           const float* __restrict__ bout, float* __restrict__ out) {
    __shared__ float srow[4][D];
    int r = threadIdx.x >> 6;
    int o = threadIdx.x & 63;
    int c = blockIdx.x * 4 + r;
    for (int t = threadIdx.x; t < 4 * D; t += 256) {
        int rr = blockIdx.x * 4 + (t >> 8);
        unsigned short h = xc[(size_t)rr * D + (t & 255)];
        srow[t >> 8][t & 255] = __uint_as_float(((unsigned)h) << 16);
    }
    __syncthreads();
    float s = 0.f;
    const float* wo = Wout + o * D;
    for (int k = 0; k < D; ++k) s += srow[r][k] * wo[k];
    out[(size_t)c * NOUTD + o] = s + bout[o];
}

// ---------------- orchestration ---------------------------------------------
extern "C" void kernel_launch(void* const* d_in, const int* in_sizes, int n_in,
                              void* d_out, int out_size, void* d_ws, size_t ws_size,
                              hipStream_t stream) {
    const float* x_gene = (const float*)d_in[0];
    const float* x_cell = (const float*)d_in[1];
    const int*   src_g2c = (const int*)d_in[2];
    const int*   dst_g2c = (const int*)d_in[3];
    const int*   src_c2g = (const int*)d_in[4];
    const int*   dst_c2g = (const int*)d_in[5];
    const float* w_g2c = (const float*)d_in[8];
    const float* w_c2g = (const float*)d_in[9];
    const float* w_gg  = (const float*)d_in[10];
    const float* w_cc  = (const float*)d_in[11];
    const float* Wrel  = (const float*)d_in[12];
    const float* brel  = (const float*)d_in[13];
    const float* Wroot = (const float*)d_in[14];
    const float* Wout  = (const float*)d_in[15];
    const float* bout  = (const float*)d_in[16];
    float* out = (float*)d_out;

    char* p = (char*)d_ws;
    auto alloc = [&](size_t bytes) -> char* {
        char* r = p;
        p += (bytes + 255) & ~(size_t)255;
        return r;
    };

    unsigned short* xg0   = (unsigned short*)alloc((size_t)NG * D * 2);
    unsigned short* vg0   = (unsigned short*)alloc((size_t)NG * D * 2);
    unsigned short* xg1   = (unsigned short*)alloc((size_t)NG * D * 2);
    unsigned short* agg_g = (unsigned short*)alloc((size_t)NG * D * 2);
    unsigned short* xc0   = (unsigned short*)alloc((size_t)NC * D * 2);
    unsigned short* vc0   = (unsigned short*)alloc((size_t)NC * D * 2);
    unsigned short* xc1   = (unsigned short*)alloc((size_t)NC * D * 2);
    unsigned short* vc1   = (unsigned short*)alloc((size_t)NC * D * 2);
    unsigned short* xc2   = (unsigned short*)alloc((size_t)NC * D * 2);
    unsigned short* aggcb = (unsigned short*)alloc((size_t)NC * D * 2);
    float* aggcf = (float*)alloc((size_t)NC * D * 4);
    int* rp_g  = (int*)alloc((NG + 1) * 4);
    int* cur_g = (int*)alloc(NG * 4);
    int* cnt_g = (int*)alloc(NG * 4);
    int* rp_c  = (int*)alloc((NC + 1) * 4);
    int* cur_c = (int*)alloc(NC * 4);
    int* cnt_c = (int*)alloc(NC * 4);
    int*   ssrc_g2c = (int*)alloc((size_t)NE * 4);
    float* sw_g2c   = (float*)alloc((size_t)NE * 4);
    int*   ssrc_c2g = (int*)alloc((size_t)NE * 4);
    float* sw_c2g   = (float*)alloc((size_t)NE * 4);
    unsigned short* Wg0 = (unsigned short*)alloc((size_t)3 * D * D * 2);
    unsigned short* Wc0 = (unsigned short*)alloc((size_t)3 * D * D * 2);
    unsigned short* Wc1 = (unsigned short*)alloc((size_t)3 * D * D * 2);
    float* bg0 = (float*)alloc(D * 4);
    float* bc0 = (float*)alloc(D * 4);
    float* bc1 = (float*)alloc(D * 4);

    // 1. zero counters
    hipMemsetAsync(cnt_g, 0, NG * 4, stream);
    hipMemsetAsync(cnt_c, 0, NC * 4, stream);

    // 2. prep inputs
    prep_x<<<(NG * D + 255) / 256, 256, 0, stream>>>(x_gene, w_gg, xg0, vg0, NG);
    prep_x<<<(NC * D + 255) / 256, 256, 0, stream>>>(x_cell, w_cc, xc0, vc0, NC);

    // 3. weights: layer0 gene (rel1, root1+root2, rel2); layer l cell (rel0, root0+root3, rel3)
    const int WW = D * D;
    build_wcat<<<(WW + 255) / 256, 256, 0, stream>>>(
        Wrel + 1 * WW, Wroot + 1 * WW, Wroot + 2 * WW, Wrel + 2 * WW,
        brel + 1 * D, brel + 2 * D, Wg0, bg0);
    build_wcat<<<(WW + 255) / 256, 256, 0, stream>>>(
        Wrel + 0 * WW, Wroot + 0 * WW, Wroot + 3 * WW, Wrel + 3 * WW,
        brel + 0 * D, brel + 3 * D, Wc0, bc0);
    build_wcat<<<(WW + 255) / 256, 256, 0, stream>>>(
        Wrel + 4 * WW, Wroot + 4 * WW, Wroot + 7 * WW, Wrel + 7 * WW,
        brel + 4 * D, brel + 7 * D, Wc1, bc1);

    // 4. CSR build (edge lists constant across layers)
    count_edges<<<(NE + 255) / 256, 256, 0, stream>>>(dst_g2c, dst_c2g, cnt_c, cnt_g);
    scan_kernel<<<1, 1024, 0, stream>>>(cnt_g, NG, rp_g, cur_g);
    scan_kernel<<<1, 1024, 0, stream>>>(cnt_c, NC, rp_c, cur_c);
    fill_edges<<<(NE + 255) / 256, 256, 0, stream>>>(
        src_g2c, dst_g2c, w_g2c, src_c2g, dst_c2g, w_c2g,
        cur_c, cur_g, ssrc_g2c, sw_g2c, ssrc_c2g, sw_c2g);

    // ---- Layer 0 ----
    hipMemsetAsync(aggcf, 0, (size_t)NC * D * 4, stream);
    agg_cell_atomic<<<NC * CELL_WAVES / 4, 256, 0, stream>>>(rp_c, ssrc_g2c, sw_g2c, xg0, aggcf);
    agg_rows_wave<<<(NG + 3) / 4, 256, 0, stream>>>(rp_g, ssrc_c2g, sw_c2g, xc0, agg_g, NG);
    f2bf_arr<<<(NC * D + 255) / 256, 256, 0, stream>>>(aggcf, aggcb, NC * D);

    // cell update L0: xc1 = relu(...), vc1 = xc1 * w_cc
    gemm_fused<<<dim3((NC + 127) / 128, 2), 256, 0, stream>>>(
        aggcb, xc0, vc0, Wc0, bc0, w_cc, xc1, vc1, NC);
    // gene update L0: xg1 = relu(...)  (layer-1 gene update is dead -> no vg1)
    gemm_fused<<<dim3((NG + 127) / 128, 2), 256, 0, stream>>>(
        agg_g, xg0, vg0, Wg0, bg0, nullptr, xg1, nullptr, NG);

    // ---- Layer 1 (cells only; gene update & c2g agg are dead) ----
    hipMemsetAsync(aggcf, 0, (size_t)NC * D * 4, stream);
    agg_cell_atomic<<<NC * CELL_WAVES / 4, 256, 0, stream>>>(rp_c, ssrc_g2c, sw_g2c, xg1, aggcf);
    f2bf_arr<<<(NC * D + 255) / 256, 256, 0, stream>>>(aggcf, aggcb, NC * D);
    gemm_fused<<<dim3((NC + 127) / 128, 2), 256, 0, stream>>>(
        aggcb, xc1, vc1, Wc1, bc1, nullptr, xc2, nullptr, NC);

    // ---- output projection ----
    out_kernel<<<NC / 4, 256, 0, stream>>>(xc2, Wout, bout, out);
}

// Round 2
// 1203.580 us; speedup vs baseline: 1.1735x; 1.1735x over previous
//
#include <hip/hip_runtime.h>

// Problem constants
static constexpr int NG   = 100000;
static constexpr int NC   = 2000;
static constexpr int D    = 256;
static constexpr int NE   = 1000000;
static constexpr int NOUTD= 64;

typedef __bf16 bf16x8 __attribute__((ext_vector_type(8)));
typedef float  f32x4  __attribute__((ext_vector_type(4)));

__device__ __forceinline__ unsigned short f2bf(float f) {
    unsigned u = __float_as_uint(f);
    u += 0x7fffu + ((u >> 16) & 1u);   // RNE
    return (unsigned short)(u >> 16);
}
__device__ __forceinline__ float bflo(unsigned x) { return __uint_as_float((x & 0xffffu) << 16); }
__device__ __forceinline__ float bfhi(unsigned x) { return __uint_as_float(x & 0xffff0000u); }

// ---------------- prep: f32 -> bf16 master copies + self-loop-scaled copy ----
__global__ void prep_x(const float* __restrict__ x, const float* __restrict__ w,
                       unsigned short* __restrict__ xo, unsigned short* __restrict__ vo,
                       int rows) {
    int i = blockIdx.x * blockDim.x + threadIdx.x;
    if (i >= rows * D) return;
    float xv = x[i];
    float wv = w[i >> 8];
    xo[i] = f2bf(xv);
    vo[i] = f2bf(xv * wv);
}

// ---------------- build concatenated bf16 weights [3][256][256] + bias sums --
__global__ void build_wcat(const float* __restrict__ Wa,  const float* __restrict__ Wra,
                           const float* __restrict__ Wrb, const float* __restrict__ Wb,
                           const float* __restrict__ ba,  const float* __restrict__ bb,
                           unsigned short* __restrict__ wout, float* __restrict__ bsum) {
    int i = blockIdx.x * blockDim.x + threadIdx.x;
    if (i >= D * D) return;
    wout[i]           = f2bf(Wa[i]);
    wout[D*D + i]     = f2bf(Wra[i] + Wrb[i]);
    wout[2*D*D + i]   = f2bf(Wb[i]);
    if (i < D) bsum[i] = ba[i] + bb[i];
}

// ---------------- CSR build -------------------------------------------------
__global__ void count_edges(const int* __restrict__ dst_g2c, const int* __restrict__ dst_c2g,
                            int* __restrict__ cnt_c, int* __restrict__ cnt_g) {
    int e = blockIdx.x * blockDim.x + threadIdx.x;
    if (e >= NE) return;
    atomicAdd(&cnt_c[dst_g2c[e]], 1);
    atomicAdd(&cnt_g[dst_c2g[e]], 1);
}

// ---- 3-phase multi-block exclusive scan (256 blocks x 256 threads) ---------
static constexpr int SCAN_NB = 256;
static constexpr int SCAN_NT = 256;

__global__ __launch_bounds__(256) void scan_phaseA(const int* __restrict__ cnt, int n,
                                                   int* __restrict__ partials) {
    __shared__ int sd[SCAN_NT];
    int chunk = (n + SCAN_NB - 1) / SCAN_NB;
    int ts = (chunk + SCAN_NT - 1) / SCAN_NT;
    int bstart = blockIdx.x * chunk;
    int bend = bstart + chunk; if (bend > n) bend = n;
    int start = bstart + threadIdx.x * ts;
    int end = start + ts; if (end > bend) end = bend;
    int sum = 0;
    for (int j = start; j < end; ++j) sum += cnt[j];
    sd[threadIdx.x] = sum;
    __syncthreads();
    for (int off = SCAN_NT / 2; off > 0; off >>= 1) {
        if (threadIdx.x < off) sd[threadIdx.x] += sd[threadIdx.x + off];
        __syncthreads();
    }
    if (threadIdx.x == 0) partials[blockIdx.x] = sd[0];
}

__global__ __launch_bounds__(256) void scan_phaseB(const int* __restrict__ partials,
                                                   int* __restrict__ blockoff,
                                                   int* __restrict__ rp, int n) {
    __shared__ int sd[SCAN_NB];
    int t = threadIdx.x;
    int v = partials[t];
    sd[t] = v;
    __syncthreads();
    for (int off = 1; off < SCAN_NB; off <<= 1) {
        int u = (t >= off) ? sd[t - off] : 0;
        __syncthreads();
        sd[t] += u;
        __syncthreads();
    }
    blockoff[t] = sd[t] - v;            // exclusive prefix of block sums
    if (t == SCAN_NB - 1) rp[n] = sd[SCAN_NB - 1];
}

__global__ __launch_bounds__(256) void scan_phaseC(const int* __restrict__ cnt, int n,
                                                   const int* __restrict__ blockoff,
                                                   int* __restrict__ rp, int* __restrict__ cur) {
    __shared__ int sd[SCAN_NT];
    int chunk = (n + SCAN_NB - 1) / SCAN_NB;
    int ts = (chunk + SCAN_NT - 1) / SCAN_NT;
    int bstart = blockIdx.x * chunk;
    int bend = bstart + chunk; if (bend > n) bend = n;
    int start = bstart + threadIdx.x * ts;
    int end = start + ts; if (end > bend) end = bend;
    int sum = 0;
    for (int j = start; j < end; ++j) sum += cnt[j];
    sd[threadIdx.x] = sum;
    __syncthreads();
    for (int off = 1; off < SCAN_NT; off <<= 1) {
        int u = (threadIdx.x >= off) ? sd[threadIdx.x - off] : 0;
        __syncthreads();
        sd[threadIdx.x] += u;
        __syncthreads();
    }
    int run = blockoff[blockIdx.x] + sd[threadIdx.x] - sum;  // exclusive within grid
    for (int j = start; j < end; ++j) {
        rp[j] = run; cur[j] = run; run += cnt[j];
    }
}

__global__ void fill_edges(const int* __restrict__ src_g2c, const int* __restrict__ dst_g2c,
                           const float* __restrict__ w_g2c,
                           const int* __restrict__ src_c2g, const int* __restrict__ dst_c2g,
                           const float* __restrict__ w_c2g,
                           int* __restrict__ cur_c, int* __restrict__ cur_g,
                           int* __restrict__ ssrc_g2c, float* __restrict__ sw_g2c,
                           int* __restrict__ ssrc_c2g, float* __restrict__ sw_c2g) {
    int e = blockIdx.x * blockDim.x + threadIdx.x;
    if (e >= NE) return;
    {
        int d = dst_g2c[e];
        int p = atomicAdd(&cur_c[d], 1);
        ssrc_g2c[p] = src_g2c[e];
        sw_g2c[p]   = w_g2c[e];
    }
    {
        int d = dst_c2g[e];
        int p = atomicAdd(&cur_g[d], 1);
        ssrc_c2g[p] = src_c2g[e];
        sw_c2g[p]   = w_c2g[e];
    }
}

// ---------------- aggregation: one wave per destination row (genes) ---------
__global__ void agg_rows_wave(const int* __restrict__ rp, const int* __restrict__ ssrc,
                              const float* __restrict__ sw, const unsigned short* __restrict__ xsrc,
                              unsigned short* __restrict__ aggout, int nrows) {
    int wave = (blockIdx.x * blockDim.x + threadIdx.x) >> 6;
    int lane = threadIdx.x & 63;
    if (wave >= nrows) return;
    int j0 = rp[wave], j1 = rp[wave + 1];
    float a0 = 0.f, a1 = 0.f, a2 = 0.f, a3 = 0.f;
    for (int j = j0; j < j1; ++j) {
        int s = ssrc[j];
        float w = sw[j];
        uint2 pk = *reinterpret_cast<const uint2*>(xsrc + (size_t)s * D + lane * 4);
        a0 += w * bflo(pk.x); a1 += w * bfhi(pk.x);
        a2 += w * bflo(pk.y); a3 += w * bfhi(pk.y);
    }
    uint2 o;
    o.x = (unsigned)f2bf(a0) | ((unsigned)f2bf(a1) << 16);
    o.y = (unsigned)f2bf(a2) | ((unsigned)f2bf(a3) << 16);
    *reinterpret_cast<uint2*>(aggout + (size_t)wave * D + lane * 4) = o;
}

// ---------------- aggregation: 8 waves per cell row, f32 atomics ------------
static constexpr int CELL_WAVES = 8;
__global__ void agg_cell_atomic(const int* __restrict__ rp, const int* __restrict__ ssrc,
                                const float* __restrict__ sw, const unsigned short* __restrict__ xg,
                                float* __restrict__ agg) {
    int gwave = (blockIdx.x * blockDim.x + threadIdx.x) >> 6;
    int lane  = threadIdx.x & 63;
    int c = gwave / CELL_WAVES, s = gwave % CELL_WAVES;
    if (c >= NC) return;
    int j0 = rp[c], j1 = rp[c + 1];
    int deg = j1 - j0;
    if (deg <= 0) return;
    int chunk = (deg + CELL_WAVES - 1) / CELL_WAVES;
    int a = j0 + s * chunk;
    int b = a + chunk; if (b > j1) b = j1;
    if (a >= b) return;
    float a0 = 0.f, a1 = 0.f, a2 = 0.f, a3 = 0.f;
    for (int j = a; j < b; ++j) {
        int src = ssrc[j];
        float w = sw[j];
        uint2 pk = *reinterpret_cast<const uint2*>(xg + (size_t)src * D + lane * 4);
        a0 += w * bflo(pk.x); a1 += w * bfhi(pk.x);
        a2 += w * bflo(pk.y); a3 += w * bfhi(pk.y);
    }
    float* o = agg + (size_t)c * D + lane * 4;
    atomicAdd(o + 0, a0); atomicAdd(o + 1, a1);
    atomicAdd(o + 2, a2); atomicAdd(o + 3, a3);
}

__global__ void f2bf_arr(const float* __restrict__ in, unsigned short* __restrict__ out, int n) {
    int i = blockIdx.x * blockDim.x + threadIdx.x;
    if (i < n) out[i] = f2bf(in[i]);
}

// ---------------- fused GEMM: relu(cat(A0,A1,A2) @ Wcat^T + bias) -----------
// Each wave: 64x64 tile via 4x4 grid of 16x16x32 bf16 MFMAs. Block: 4 waves =
// 128Mx128N; gridDim.y=2 covers N=256.
__global__ __launch_bounds__(256, 2) void gemm_fused(
        const unsigned short* __restrict__ A0,
        const unsigned short* __restrict__ A1,
        const unsigned short* __restrict__ A2,
        const unsigned short* __restrict__ W,     // [3][256][256] bf16
        const float* __restrict__ bias,           // [256]
        const float* __restrict__ wrow,           // nullable per-row scale for vout
        unsigned short* __restrict__ xout,        // [M,256] bf16
        unsigned short* __restrict__ vout,        // nullable [M,256] bf16
        int M) {
    int wave = threadIdx.x >> 6;
    int lane = threadIdx.x & 63;
    int m0 = blockIdx.x * 128 + (wave >> 1) * 64;
    int n0 = blockIdx.y * 128 + (wave & 1) * 64;
    int lm = lane & 15, lq = lane >> 4;

    f32x4 acc[4][4];
#pragma unroll
    for (int i = 0; i < 4; ++i)
#pragma unroll
        for (int j = 0; j < 4; ++j) acc[i][j] = f32x4{0.f, 0.f, 0.f, 0.f};

    int rA[4];
#pragma unroll
    for (int i = 0; i < 4; ++i) {
        int r = m0 + i * 16 + lm;
        rA[i] = r < M ? r : M - 1;
    }

    const unsigned short* Aseg[3] = {A0, A1, A2};
#pragma unroll
    for (int s = 0; s < 3; ++s) {
        const unsigned short* As = Aseg[s];
        const unsigned short* Ws = W + s * D * D;
        for (int k = 0; k < D; k += 32) {
            int ka = k + lq * 8;
            bf16x8 a[4], b[4];
#pragma unroll
            for (int i = 0; i < 4; ++i)
                a[i] = *reinterpret_cast<const bf16x8*>(As + (size_t)rA[i] * D + ka);
#pragma unroll
            for (int j = 0; j < 4; ++j)
                b[j] = *reinterpret_cast<const bf16x8*>(Ws + (size_t)(n0 + j * 16 + lm) * D + ka);
#pragma unroll
            for (int i = 0; i < 4; ++i)
#pragma unroll
                for (int j = 0; j < 4; ++j)
                    acc[i][j] = __builtin_amdgcn_mfma_f32_16x16x32_bf16(a[i], b[j], acc[i][j], 0, 0, 0);
        }
    }

    // epilogue: C[row=m0+i*16+lq*4+r][col=n0+j*16+lm]
#pragma unroll
    for (int i = 0; i < 4; ++i) {
#pragma unroll
        for (int r = 0; r < 4; ++r) {
            int rr = m0 + i * 16 + lq * 4 + r;
            if (rr >= M) continue;
            float wr = wrow ? wrow[rr] : 0.f;
#pragma unroll
            for (int j = 0; j < 4; ++j) {
                int col = n0 + j * 16 + lm;
                float v = acc[i][j][r] + bias[col];
                v = v > 0.f ? v : 0.f;
                xout[(size_t)rr * D + col] = f2bf(v);
                if (vout) vout[(size_t)rr * D + col] = f2bf(v * wr);
            }
        }
    }
}

// ---------------- final projection: out = xc2 @ Wout^T + bout (fp32) --------
__global__ void out_kernel(const unsigned short* __restrict__ xc, const float* __restrict__ Wout,
                           const float* __restrict__ bout, float* __restrict__ out) {
    __shared__ float srow[4][D];
    int r = threadIdx.x >> 6;
    int o = threadIdx.x & 63;
    int c = blockIdx.x * 4 + r;
    for (int t = threadIdx.x; t < 4 * D; t += 256) {
        int rr = blockIdx.x * 4 + (t >> 8);
        unsigned short h = xc[(size_t)rr * D + (t & 255)];
        srow[t >> 8][t & 255] = __uint_as_float(((unsigned)h) << 16);
    }
    __syncthreads();
    float s = 0.f;
    const float* wo = Wout + o * D;
    for (int k = 0; k < D; ++k) s += srow[r][k] * wo[k];
    out[(size_t)c * NOUTD + o] = s + bout[o];
}

// ---------------- orchestration ---------------------------------------------
extern "C" void kernel_launch(void* const* d_in, const int* in_sizes, int n_in,
                              void* d_out, int out_size, void* d_ws, size_t ws_size,
                              hipStream_t stream) {
    const float* x_gene = (const float*)d_in[0];
    const float* x_cell = (const float*)d_in[1];
    const int*   src_g2c = (const int*)d_in[2];
    const int*   dst_g2c = (const int*)d_in[3];
    const int*   src_c2g = (const int*)d_in[4];
    const int*   dst_c2g = (const int*)d_in[5];
    const float* w_g2c = (const float*)d_in[8];
    const float* w_c2g = (const float*)d_in[9];
    const float* w_gg  = (const float*)d_in[10];
    const float* w_cc  = (const float*)d_in[11];
    const float* Wrel  = (const float*)d_in[12];
    const float* brel  = (const float*)d_in[13];
    const float* Wroot = (const float*)d_in[14];
    const float* Wout  = (const float*)d_in[15];
    const float* bout  = (const float*)d_in[16];
    float* out = (float*)d_out;

    char* p = (char*)d_ws;
    auto alloc = [&](size_t bytes) -> char* {
        char* r = p;
        p += (bytes + 255) & ~(size_t)255;
        return r;
    };

    unsigned short* xg0   = (unsigned short*)alloc((size_t)NG * D * 2);
    unsigned short* vg0   = (unsigned short*)alloc((size_t)NG * D * 2);
    unsigned short* xg1   = (unsigned short*)alloc((size_t)NG * D * 2);
    unsigned short* agg_g = (unsigned short*)alloc((size_t)NG * D * 2);
    unsigned short* xc0   = (unsigned short*)alloc((size_t)NC * D * 2);
    unsigned short* vc0   = (unsigned short*)alloc((size_t)NC * D * 2);
    unsigned short* xc1   = (unsigned short*)alloc((size_t)NC * D * 2);
    unsigned short* vc1   = (unsigned short*)alloc((size_t)NC * D * 2);
    unsigned short* xc2   = (unsigned short*)alloc((size_t)NC * D * 2);
    unsigned short* aggcb = (unsigned short*)alloc((size_t)NC * D * 2);
    float* aggcf = (float*)alloc((size_t)NC * D * 4);
    int* rp_g  = (int*)alloc((NG + 1) * 4);
    int* cur_g = (int*)alloc(NG * 4);
    int* cnt_g = (int*)alloc(NG * 4);
    int* rp_c  = (int*)alloc((NC + 1) * 4);
    int* cur_c = (int*)alloc(NC * 4);
    int* cnt_c = (int*)alloc(NC * 4);
    int*   ssrc_g2c = (int*)alloc((size_t)NE * 4);
    float* sw_g2c   = (float*)alloc((size_t)NE * 4);
    int*   ssrc_c2g = (int*)alloc((size_t)NE * 4);
    float* sw_c2g   = (float*)alloc((size_t)NE * 4);
    unsigned short* Wg0 = (unsigned short*)alloc((size_t)3 * D * D * 2);
    unsigned short* Wc0 = (unsigned short*)alloc((size_t)3 * D * D * 2);
    unsigned short* Wc1 = (unsigned short*)alloc((size_t)3 * D * D * 2);
    float* bg0 = (float*)alloc(D * 4);
    float* bc0 = (float*)alloc(D * 4);
    float* bc1 = (float*)alloc(D * 4);
    int* part_g = (int*)alloc(SCAN_NB * 4);
    int* boff_g = (int*)alloc(SCAN_NB * 4);
    int* part_c = (int*)alloc(SCAN_NB * 4);
    int* boff_c = (int*)alloc(SCAN_NB * 4);

    // 1. zero counters
    hipMemsetAsync(cnt_g, 0, NG * 4, stream);
    hipMemsetAsync(cnt_c, 0, NC * 4, stream);

    // 2. prep inputs
    prep_x<<<(NG * D + 255) / 256, 256, 0, stream>>>(x_gene, w_gg, xg0, vg0, NG);
    prep_x<<<(NC * D + 255) / 256, 256, 0, stream>>>(x_cell, w_cc, xc0, vc0, NC);

    // 3. weights: layer0 gene (rel1, root1+root2, rel2); layer l cell (rel0, root0+root3, rel3)
    const int WW = D * D;
    build_wcat<<<(WW + 255) / 256, 256, 0, stream>>>(
        Wrel + 1 * WW, Wroot + 1 * WW, Wroot + 2 * WW, Wrel + 2 * WW,
        brel + 1 * D, brel + 2 * D, Wg0, bg0);
    build_wcat<<<(WW + 255) / 256, 256, 0, stream>>>(
        Wrel + 0 * WW, Wroot + 0 * WW, Wroot + 3 * WW, Wrel + 3 * WW,
        brel + 0 * D, brel + 3 * D, Wc0, bc0);
    build_wcat<<<(WW + 255) / 256, 256, 0, stream>>>(
        Wrel + 4 * WW, Wroot + 4 * WW, Wroot + 7 * WW, Wrel + 7 * WW,
        brel + 4 * D, brel + 7 * D, Wc1, bc1);

    // 4. CSR build (edge lists constant across layers)
    count_edges<<<(NE + 255) / 256, 256, 0, stream>>>(dst_g2c, dst_c2g, cnt_c, cnt_g);
    scan_phaseA<<<SCAN_NB, SCAN_NT, 0, stream>>>(cnt_g, NG, part_g);
    scan_phaseA<<<SCAN_NB, SCAN_NT, 0, stream>>>(cnt_c, NC, part_c);
    scan_phaseB<<<1, SCAN_NB, 0, stream>>>(part_g, boff_g, rp_g, NG);
    scan_phaseB<<<1, SCAN_NB, 0, stream>>>(part_c, boff_c, rp_c, NC);
    scan_phaseC<<<SCAN_NB, SCAN_NT, 0, stream>>>(cnt_g, NG, boff_g, rp_g, cur_g);
    scan_phaseC<<<SCAN_NB, SCAN_NT, 0, stream>>>(cnt_c, NC, boff_c, rp_c, cur_c);
    fill_edges<<<(NE + 255) / 256, 256, 0, stream>>>(
        src_g2c, dst_g2c, w_g2c, src_c2g, dst_c2g, w_c2g,
        cur_c, cur_g, ssrc_g2c, sw_g2c, ssrc_c2g, sw_c2g);

    // ---- Layer 0 ----
    hipMemsetAsync(aggcf, 0, (size_t)NC * D * 4, stream);
    agg_cell_atomic<<<NC * CELL_WAVES / 4, 256, 0, stream>>>(rp_c, ssrc_g2c, sw_g2c, xg0, aggcf);
    agg_rows_wave<<<(NG + 3) / 4, 256, 0, stream>>>(rp_g, ssrc_c2g, sw_c2g, xc0, agg_g, NG);
    f2bf_arr<<<(NC * D + 255) / 256, 256, 0, stream>>>(aggcf, aggcb, NC * D);

    // cell update L0: xc1 = relu(...), vc1 = xc1 * w_cc
    gemm_fused<<<dim3((NC + 127) / 128, 2), 256, 0, stream>>>(
        aggcb, xc0, vc0, Wc0, bc0, w_cc, xc1, vc1, NC);
    // gene update L0: xg1 = relu(...)  (layer-1 gene update is dead -> no vg1)
    gemm_fused<<<dim3((NG + 127) / 128, 2), 256, 0, stream>>>(
        agg_g, xg0, vg0, Wg0, bg0, nullptr, xg1, nullptr, NG);

    // ---- Layer 1 (cells only; gene update & c2g agg are dead) ----
    hipMemsetAsync(aggcf, 0, (size_t)NC * D * 4, stream);
    agg_cell_atomic<<<NC * CELL_WAVES / 4, 256, 0, stream>>>(rp_c, ssrc_g2c, sw_g2c, xg1, aggcf);
    f2bf_arr<<<(NC * D + 255) / 256, 256, 0, stream>>>(aggcf, aggcb, NC * D);
    gemm_fused<<<dim3((NC + 127) / 128, 2), 256, 0, stream>>>(
        aggcb, xc1, vc1, Wc1, bc1, nullptr, xc2, nullptr, NC);

    // ---- output projection ----
    out_kernel<<<NC / 4, 256, 0, stream>>>(xc2, Wout, bout, out);
}

// Round 3
// 963.553 us; speedup vs baseline: 1.4658x; 1.2491x over previous
//
#include <hip/hip_runtime.h>

// Problem constants
static constexpr int NG   = 100000;
static constexpr int NC   = 2000;
static constexpr int D    = 256;
static constexpr int NE   = 1000000;
static constexpr int NOUTD= 64;
static constexpr int KCAT = 768;          // concatenated K: [agg | x | v]

typedef __bf16 bf16x8 __attribute__((ext_vector_type(8)));
typedef float  f32x4  __attribute__((ext_vector_type(4)));

__device__ __forceinline__ unsigned short f2bf(float f) {
    unsigned u = __float_as_uint(f);
    u += 0x7fffu + ((u >> 16) & 1u);   // RNE
    return (unsigned short)(u >> 16);
}
__device__ __forceinline__ float bflo(unsigned x) { return __uint_as_float((x & 0xffffu) << 16); }
__device__ __forceinline__ float bfhi(unsigned x) { return __uint_as_float(x & 0xffff0000u); }

// async global->LDS, 16B per lane. LDS dest is wave-uniform base + lane*16:
// callers must pass lds addresses contiguous in lane order within each wave.
__device__ __forceinline__ void async16(const void* g, void* l) {
    __builtin_amdgcn_global_load_lds(
        (const __attribute__((address_space(1))) void*)g,
        (__attribute__((address_space(3))) void*)l, 16, 0, 0);
}

// ---------------- prep: f32 -> bf16 into Acat cols [256..512) and [512..768)
__global__ void prep_x(const float* __restrict__ x, const float* __restrict__ w,
                       unsigned short* __restrict__ dx, unsigned short* __restrict__ dv,
                       long stride, int rows) {
    int i = blockIdx.x * blockDim.x + threadIdx.x;   // one per 4 elements
    if (i >= rows * (D / 4)) return;
    int row = i >> 6, c4 = (i & 63) * 4;
    float4 xv = *reinterpret_cast<const float4*>(x + (size_t)row * D + c4);
    float wv = w[row];
    uint2 ox, ov;
    ox.x = (unsigned)f2bf(xv.x) | ((unsigned)f2bf(xv.y) << 16);
    ox.y = (unsigned)f2bf(xv.z) | ((unsigned)f2bf(xv.w) << 16);
    ov.x = (unsigned)f2bf(xv.x * wv) | ((unsigned)f2bf(xv.y * wv) << 16);
    ov.y = (unsigned)f2bf(xv.z * wv) | ((unsigned)f2bf(xv.w * wv) << 16);
    *reinterpret_cast<uint2*>(dx + (size_t)row * stride + c4) = ox;
    *reinterpret_cast<uint2*>(dv + (size_t)row * stride + c4) = ov;
}

// ---------------- build concatenated bf16 weights [256][768] + bias sums ----
__global__ void build_wcat(const float* __restrict__ Wa,  const float* __restrict__ Wra,
                           const float* __restrict__ Wrb, const float* __restrict__ Wb,
                           const float* __restrict__ ba,  const float* __restrict__ bb,
                           unsigned short* __restrict__ wout, float* __restrict__ bsum) {
    int i = blockIdx.x * blockDim.x + threadIdx.x;
    if (i >= D * D) return;
    int n = i >> 8, k = i & 255;
    wout[(size_t)n * KCAT + k]        = f2bf(Wa[i]);
    wout[(size_t)n * KCAT + 256 + k]  = f2bf(Wra[i] + Wrb[i]);
    wout[(size_t)n * KCAT + 512 + k]  = f2bf(Wb[i]);
    if (i < D) bsum[i] = ba[i] + bb[i];
}

// ---------------- CSR build -------------------------------------------------
__global__ void count_edges(const int* __restrict__ dst_g2c, const int* __restrict__ dst_c2g,
                            int* __restrict__ cnt_c, int* __restrict__ cnt_g) {
    int e = blockIdx.x * blockDim.x + threadIdx.x;
    if (e >= NE) return;
    atomicAdd(&cnt_c[dst_g2c[e]], 1);
    atomicAdd(&cnt_g[dst_c2g[e]], 1);
}

static constexpr int SCAN_NB = 256;
static constexpr int SCAN_NT = 256;

__global__ __launch_bounds__(256) void scan_phaseA(const int* __restrict__ cnt, int n,
                                                   int* __restrict__ partials) {
    __shared__ int sd[SCAN_NT];
    int chunk = (n + SCAN_NB - 1) / SCAN_NB;
    int ts = (chunk + SCAN_NT - 1) / SCAN_NT;
    int bstart = blockIdx.x * chunk;
    int bend = bstart + chunk; if (bend > n) bend = n;
    int start = bstart + threadIdx.x * ts;
    int end = start + ts; if (end > bend) end = bend;
    int sum = 0;
    for (int j = start; j < end; ++j) sum += cnt[j];
    sd[threadIdx.x] = sum;
    __syncthreads();
    for (int off = SCAN_NT / 2; off > 0; off >>= 1) {
        if (threadIdx.x < off) sd[threadIdx.x] += sd[threadIdx.x + off];
        __syncthreads();
    }
    if (threadIdx.x == 0) partials[blockIdx.x] = sd[0];
}

__global__ __launch_bounds__(256) void scan_phaseB(const int* __restrict__ partials,
                                                   int* __restrict__ blockoff,
                                                   int* __restrict__ rp, int n) {
    __shared__ int sd[SCAN_NB];
    int t = threadIdx.x;
    int v = partials[t];
    sd[t] = v;
    __syncthreads();
    for (int off = 1; off < SCAN_NB; off <<= 1) {
        int u = (t >= off) ? sd[t - off] : 0;
        __syncthreads();
        sd[t] += u;
        __syncthreads();
    }
    blockoff[t] = sd[t] - v;
    if (t == SCAN_NB - 1) rp[n] = sd[SCAN_NB - 1];
}

__global__ __launch_bounds__(256) void scan_phaseC(const int* __restrict__ cnt, int n,
                                                   const int* __restrict__ blockoff,
                                                   int* __restrict__ rp, int* __restrict__ cur) {
    __shared__ int sd[SCAN_NT];
    int chunk = (n + SCAN_NB - 1) / SCAN_NB;
    int ts = (chunk + SCAN_NT - 1) / SCAN_NT;
    int bstart = blockIdx.x * chunk;
    int bend = bstart + chunk; if (bend > n) bend = n;
    int start = bstart + threadIdx.x * ts;
    int end = start + ts; if (end > bend) end = bend;
    int sum = 0;
    for (int j = start; j < end; ++j) sum += cnt[j];
    sd[threadIdx.x] = sum;
    __syncthreads();
    for (int off = 1; off < SCAN_NT; off <<= 1) {
        int u = (threadIdx.x >= off) ? sd[threadIdx.x - off] : 0;
        __syncthreads();
        sd[threadIdx.x] += u;
        __syncthreads();
    }
    int run = blockoff[blockIdx.x] + sd[threadIdx.x] - sum;
    for (int j = start; j < end; ++j) {
        rp[j] = run; cur[j] = run; run += cnt[j];
    }
}

// edge payload: .x = src index, .y = weight bits
__global__ void fill_edges(const int* __restrict__ src_g2c, const int* __restrict__ dst_g2c,
                           const float* __restrict__ w_g2c,
                           const int* __restrict__ src_c2g, const int* __restrict__ dst_c2g,
                           const float* __restrict__ w_c2g,
                           int* __restrict__ cur_c, int* __restrict__ cur_g,
                           int2* __restrict__ ec, int2* __restrict__ eg) {
    int e = blockIdx.x * blockDim.x + threadIdx.x;
    if (e >= NE) return;
    {
        int d = dst_g2c[e];
        int p = atomicAdd(&cur_c[d], 1);
        ec[p] = make_int2(src_g2c[e], __float_as_int(w_g2c[e]));
    }
    {
        int d = dst_c2g[e];
        int p = atomicAdd(&cur_g[d], 1);
        eg[p] = make_int2(src_c2g[e], __float_as_int(w_c2g[e]));
    }
}

// ---------------- gene aggregation: one wave per destination row ------------
__global__ void agg_gene(const int* __restrict__ rp, const int2* __restrict__ eg,
                         const unsigned short* __restrict__ src, long sstride,
                         unsigned short* __restrict__ out, long ostride, int nrows) {
    int wave = (blockIdx.x * blockDim.x + threadIdx.x) >> 6;
    int lane = threadIdx.x & 63;
    if (wave >= nrows) return;
    int j0 = rp[wave], j1 = rp[wave + 1];
    float a0 = 0.f, a1 = 0.f, a2 = 0.f, a3 = 0.f;
    for (int j = j0; j < j1; ++j) {
        int2 e = eg[j];
        float w = __int_as_float(e.y);
        uint2 pk = *reinterpret_cast<const uint2*>(src + (size_t)e.x * sstride + lane * 4);
        a0 += w * bflo(pk.x); a1 += w * bfhi(pk.x);
        a2 += w * bflo(pk.y); a3 += w * bfhi(pk.y);
    }
    uint2 o;
    o.x = (unsigned)f2bf(a0) | ((unsigned)f2bf(a1) << 16);
    o.y = (unsigned)f2bf(a2) | ((unsigned)f2bf(a3) << 16);
    *reinterpret_cast<uint2*>(out + (size_t)wave * ostride + lane * 4) = o;
}

// ---------------- cell aggregation: one block per cell, LDS reduce ----------
__global__ __launch_bounds__(256) void agg_cell(const int* __restrict__ rp,
                                                const int2* __restrict__ ec,
                                                const unsigned short* __restrict__ src, long sstride,
                                                unsigned short* __restrict__ out, long ostride) {
    __shared__ float red[4][D];
    int c = blockIdx.x;
    int wv = threadIdx.x >> 6, ln = threadIdx.x & 63;
    int j0 = rp[c], j1 = rp[c + 1];
    float a0 = 0.f, a1 = 0.f, a2 = 0.f, a3 = 0.f;
    for (int j = j0 + wv; j < j1; j += 4) {
        int2 e = ec[j];
        float w = __int_as_float(e.y);
        uint2 pk = *reinterpret_cast<const uint2*>(src + (size_t)e.x * sstride + ln * 4);
        a0 += w * bflo(pk.x); a1 += w * bfhi(pk.x);
        a2 += w * bflo(pk.y); a3 += w * bfhi(pk.y);
    }
    red[wv][ln * 4 + 0] = a0; red[wv][ln * 4 + 1] = a1;
    red[wv][ln * 4 + 2] = a2; red[wv][ln * 4 + 3] = a3;
    __syncthreads();
    int col = threadIdx.x;
    float s = red[0][col] + red[1][col] + red[2][col] + red[3][col];
    out[(size_t)c * ostride + col] = f2bf(s);
}

// ---------------- m97-style GEMM: relu(A[M,768] @ W[256,768]^T + bias) ------
// 128x128 tile, BK=64, global_load_lds width-16, XOR-swizzled LDS.
// LDS chunk slot (r,s) holds global 16B chunk (r, s ^ (r&7)).
__global__ __launch_bounds__(256, 2) void gemm_tile(
        const unsigned short* __restrict__ A,    // [M][768]
        const unsigned short* __restrict__ W,    // [256][768]
        const float* __restrict__ bias,          // [256]
        const float* __restrict__ wrow,          // nullable per-row scale for vout
        unsigned short* __restrict__ xout, long xstride,
        unsigned short* __restrict__ vout,       // nullable, same stride
        int M) {
    __shared__ unsigned short As[128 * 64];
    __shared__ unsigned short Bs[128 * 64];
    int tid = threadIdx.x;
    int wv = tid >> 6, ln = tid & 63;
    int lm = ln & 15, lq = ln >> 4;
    int m0 = blockIdx.x * 128;
    int nb = blockIdx.y * 128;
    int m0w = m0 + (wv >> 1) * 64;
    int n0w = nb + (wv & 1) * 64;

    f32x4 acc[4][4];
#pragma unroll
    for (int i = 0; i < 4; ++i)
#pragma unroll
        for (int j = 0; j < 4; ++j) acc[i][j] = f32x4{0.f, 0.f, 0.f, 0.f};

    for (int k0 = 0; k0 < KCAT; k0 += 64) {
#pragma unroll
        for (int t = 0; t < 4; ++t) {
            int ci = t * 256 + tid;
            int r = ci >> 3, s = ci & 7;
            int cg = s ^ (r & 7);
            int row = m0 + r; if (row >= M) row = M - 1;
            async16(A + (size_t)row * KCAT + k0 + cg * 8,
                    (unsigned char*)As + ci * 16);
        }
#pragma unroll
        for (int t = 0; t < 4; ++t) {
            int ci = t * 256 + tid;
            int r = ci >> 3, s = ci & 7;
            int cg = s ^ (r & 7);
            async16(W + (size_t)(nb + r) * KCAT + k0 + cg * 8,
                    (unsigned char*)Bs + ci * 16);
        }
        __syncthreads();
#pragma unroll
        for (int kk = 0; kk < 2; ++kk) {
            bf16x8 a[4], b[4];
#pragma unroll
            for (int i = 0; i < 4; ++i) {
                int r = (wv >> 1) * 64 + i * 16 + lm;
                int c = kk * 4 + lq;
                int s = c ^ (r & 7);
                a[i] = *reinterpret_cast<const bf16x8*>(As + (r * 8 + s) * 8);
            }
#pragma unroll
            for (int j = 0; j < 4; ++j) {
                int r = (wv & 1) * 64 + j * 16 + lm;
                int c = kk * 4 + lq;
                int s = c ^ (r & 7);
                b[j] = *reinterpret_cast<const bf16x8*>(Bs + (r * 8 + s) * 8);
            }
#pragma unroll
            for (int i = 0; i < 4; ++i)
#pragma unroll
                for (int j = 0; j < 4; ++j)
                    acc[i][j] = __builtin_amdgcn_mfma_f32_16x16x32_bf16(a[i], b[j], acc[i][j], 0, 0, 0);
        }
        __syncthreads();
    }

    // epilogue: C[row = m0w + i*16 + lq*4 + r][col = n0w + j*16 + lm]
#pragma unroll
    for (int i = 0; i < 4; ++i) {
#pragma unroll
        for (int r4 = 0; r4 < 4; ++r4) {
            int rr = m0w + i * 16 + lq * 4 + r4;
            if (rr >= M) continue;
            float wr = wrow ? wrow[rr] : 0.f;
#pragma unroll
            for (int j = 0; j < 4; ++j) {
                int col = n0w + j * 16 + lm;
                float v = acc[i][j][r4] + bias[col];
                v = v > 0.f ? v : 0.f;
                xout[(size_t)rr * xstride + col] = f2bf(v);
                if (vout) vout[(size_t)rr * xstride + col] = f2bf(v * wr);
            }
        }
    }
}

// ---------------- final projection: out = xc2 @ Wout^T + bout (fp32) --------
__global__ void out_kernel(const unsigned short* __restrict__ xc, const float* __restrict__ Wout,
                           const float* __restrict__ bout, float* __restrict__ out) {
    __shared__ float srow[4][D];
    int r = threadIdx.x >> 6;
    int o = threadIdx.x & 63;
    int c = blockIdx.x * 4 + r;
    for (int t = threadIdx.x; t < 4 * D; t += 256) {
        int rr = blockIdx.x * 4 + (t >> 8);
        unsigned short h = xc[(size_t)rr * D + (t & 255)];
        srow[t >> 8][t & 255] = __uint_as_float(((unsigned)h) << 16);
    }
    __syncthreads();
    float s = 0.f;
    const float* wo = Wout + o * D;
    for (int k = 0; k < D; ++k) s += srow[r][k] * wo[k];
    out[(size_t)c * NOUTD + o] = s + bout[o];
}

// ---------------- orchestration ---------------------------------------------
extern "C" void kernel_launch(void* const* d_in, const int* in_sizes, int n_in,
                              void* d_out, int out_size, void* d_ws, size_t ws_size,
                              hipStream_t stream) {
    const float* x_gene = (const float*)d_in[0];
    const float* x_cell = (const float*)d_in[1];
    const int*   src_g2c = (const int*)d_in[2];
    const int*   dst_g2c = (const int*)d_in[3];
    const int*   src_c2g = (const int*)d_in[4];
    const int*   dst_c2g = (const int*)d_in[5];
    const float* w_g2c = (const float*)d_in[8];
    const float* w_c2g = (const float*)d_in[9];
    const float* w_gg  = (const float*)d_in[10];
    const float* w_cc  = (const float*)d_in[11];
    const float* Wrel  = (const float*)d_in[12];
    const float* brel  = (const float*)d_in[13];
    const float* Wroot = (const float*)d_in[14];
    const float* Wout  = (const float*)d_in[15];
    const float* bout  = (const float*)d_in[16];
    float* out = (float*)d_out;

    char* p = (char*)d_ws;
    auto alloc = [&](size_t bytes) -> char* {
        char* r = p;
        p += (bytes + 255) & ~(size_t)255;
        return r;
    };

    // Acat layouts: [rows][768] = [agg(0..255) | x(256..511) | v(512..767)]
    unsigned short* Acat_g  = (unsigned short*)alloc((size_t)NG * KCAT * 2);
    unsigned short* xg1     = (unsigned short*)alloc((size_t)NG * D * 2);
    unsigned short* Acat_c0 = (unsigned short*)alloc((size_t)NC * KCAT * 2);
    unsigned short* Acat_c1 = (unsigned short*)alloc((size_t)NC * KCAT * 2);
    unsigned short* xc2     = (unsigned short*)alloc((size_t)NC * D * 2);
    int* rp_g  = (int*)alloc((NG + 1) * 4);
    int* cur_g = (int*)alloc(NG * 4);
    int* cnt_g = (int*)alloc(NG * 4);
    int* rp_c  = (int*)alloc((NC + 1) * 4);
    int* cur_c = (int*)alloc(NC * 4);
    int* cnt_c = (int*)alloc(NC * 4);
    int2* ec = (int2*)alloc((size_t)NE * 8);   // g2c edges grouped by cell
    int2* eg = (int2*)alloc((size_t)NE * 8);   // c2g edges grouped by gene
    unsigned short* Wg0 = (unsigned short*)alloc((size_t)D * KCAT * 2);
    unsigned short* Wc0 = (unsigned short*)alloc((size_t)D * KCAT * 2);
    unsigned short* Wc1 = (unsigned short*)alloc((size_t)D * KCAT * 2);
    float* bg0 = (float*)alloc(D * 4);
    float* bc0 = (float*)alloc(D * 4);
    float* bc1 = (float*)alloc(D * 4);
    int* part_g = (int*)alloc(SCAN_NB * 4);
    int* boff_g = (int*)alloc(SCAN_NB * 4);
    int* part_c = (int*)alloc(SCAN_NB * 4);
    int* boff_c = (int*)alloc(SCAN_NB * 4);

    hipMemsetAsync(cnt_g, 0, NG * 4, stream);
    hipMemsetAsync(cnt_c, 0, NC * 4, stream);

    // prep: bf16 x and v into Acat col-blocks
    prep_x<<<(NG * 64 + 255) / 256, 256, 0, stream>>>(x_gene, w_gg, Acat_g + 256, Acat_g + 512, KCAT, NG);
    prep_x<<<(NC * 64 + 255) / 256, 256, 0, stream>>>(x_cell, w_cc, Acat_c0 + 256, Acat_c0 + 512, KCAT, NC);

    // weights: gene L0 (rel1, root1+root2, rel2); cell Ll (rel0, root0+root3, rel3)
    const int WW = D * D;
    build_wcat<<<(WW + 255) / 256, 256, 0, stream>>>(
        Wrel + 1 * WW, Wroot + 1 * WW, Wroot + 2 * WW, Wrel + 2 * WW,
        brel + 1 * D, brel + 2 * D, Wg0, bg0);
    build_wcat<<<(WW + 255) / 256, 256, 0, stream>>>(
        Wrel + 0 * WW, Wroot + 0 * WW, Wroot + 3 * WW, Wrel + 3 * WW,
        brel + 0 * D, brel + 3 * D, Wc0, bc0);
    build_wcat<<<(WW + 255) / 256, 256, 0, stream>>>(
        Wrel + 4 * WW, Wroot + 4 * WW, Wroot + 7 * WW, Wrel + 7 * WW,
        brel + 4 * D, brel + 7 * D, Wc1, bc1);

    // CSR build
    count_edges<<<(NE + 255) / 256, 256, 0, stream>>>(dst_g2c, dst_c2g, cnt_c, cnt_g);
    scan_phaseA<<<SCAN_NB, SCAN_NT, 0, stream>>>(cnt_g, NG, part_g);
    scan_phaseA<<<SCAN_NB, SCAN_NT, 0, stream>>>(cnt_c, NC, part_c);
    scan_phaseB<<<1, SCAN_NB, 0, stream>>>(part_g, boff_g, rp_g, NG);
    scan_phaseB<<<1, SCAN_NB, 0, stream>>>(part_c, boff_c, rp_c, NC);
    scan_phaseC<<<SCAN_NB, SCAN_NT, 0, stream>>>(cnt_g, NG, boff_g, rp_g, cur_g);
    scan_phaseC<<<SCAN_NB, SCAN_NT, 0, stream>>>(cnt_c, NC, boff_c, rp_c, cur_c);
    fill_edges<<<(NE + 255) / 256, 256, 0, stream>>>(
        src_g2c, dst_g2c, w_g2c, src_c2g, dst_c2g, w_c2g,
        cur_c, cur_g, ec, eg);

    // ---- Layer 0 aggregations ----
    agg_cell<<<NC, 256, 0, stream>>>(rp_c, ec, Acat_g + 256, KCAT, Acat_c0, KCAT);
    agg_gene<<<(NG + 3) / 4, 256, 0, stream>>>(rp_g, eg, Acat_c0 + 256, KCAT, Acat_g, KCAT, NG);

    // ---- Layer 0 updates ----
    // cell: xc1/vc1 written straight into Acat_c1
    gemm_tile<<<dim3((NC + 127) / 128, 2), 256, 0, stream>>>(
        Acat_c0, Wc0, bc0, w_cc, Acat_c1 + 256, KCAT, Acat_c1 + 512, NC);
    // gene: xg1 plain [NG][256]
    gemm_tile<<<dim3((NG + 127) / 128, 2), 256, 0, stream>>>(
        Acat_g, Wg0, bg0, nullptr, xg1, D, nullptr, NG);

    // ---- Layer 1 (cells only) ----
    agg_cell<<<NC, 256, 0, stream>>>(rp_c, ec, xg1, D, Acat_c1, KCAT);
    gemm_tile<<<dim3((NC + 127) / 128, 2), 256, 0, stream>>>(
        Acat_c1, Wc1, bc1, nullptr, xc2, D, nullptr, NC);

    // ---- output projection ----
    out_kernel<<<NC / 4, 256, 0, stream>>>(xc2, Wout, bout, out);
}

// Round 4
// 767.980 us; speedup vs baseline: 1.8391x; 1.2547x over previous
//
#include <hip/hip_runtime.h>

// Problem constants
static constexpr int NG   = 100000;
static constexpr int NC   = 2000;
static constexpr int D    = 256;
static constexpr int NE   = 1000000;
static constexpr int NOUTD= 64;
static constexpr int KCAT = 768;          // concatenated K: [agg | x | v]

typedef __bf16 bf16x8 __attribute__((ext_vector_type(8)));
typedef float  f32x4  __attribute__((ext_vector_type(4)));

__device__ __forceinline__ unsigned short f2bf(float f) {
    unsigned u = __float_as_uint(f);
    u += 0x7fffu + ((u >> 16) & 1u);   // RNE
    return (unsigned short)(u >> 16);
}
__device__ __forceinline__ float bflo(unsigned x) { return __uint_as_float((x & 0xffffu) << 16); }
__device__ __forceinline__ float bfhi(unsigned x) { return __uint_as_float(x & 0xffff0000u); }

__device__ __forceinline__ void async16(const void* g, void* l) {
    __builtin_amdgcn_global_load_lds(
        (const __attribute__((address_space(1))) void*)g,
        (__attribute__((address_space(3))) void*)l, 16, 0, 0);
}

// ---------------- prep: f32 -> bf16 into Acat cols [256..512) and [512..768)
__global__ void prep_x(const float* __restrict__ x, const float* __restrict__ w,
                       unsigned short* __restrict__ dx, unsigned short* __restrict__ dv,
                       long stride, int rows) {
    int i = blockIdx.x * blockDim.x + threadIdx.x;   // one per 4 elements
    if (i >= rows * (D / 4)) return;
    int row = i >> 6, c4 = (i & 63) * 4;
    float4 xv = *reinterpret_cast<const float4*>(x + (size_t)row * D + c4);
    float wv = w[row];
    uint2 ox, ov;
    ox.x = (unsigned)f2bf(xv.x) | ((unsigned)f2bf(xv.y) << 16);
    ox.y = (unsigned)f2bf(xv.z) | ((unsigned)f2bf(xv.w) << 16);
    ov.x = (unsigned)f2bf(xv.x * wv) | ((unsigned)f2bf(xv.y * wv) << 16);
    ov.y = (unsigned)f2bf(xv.z * wv) | ((unsigned)f2bf(xv.w * wv) << 16);
    *reinterpret_cast<uint2*>(dx + (size_t)row * stride + c4) = ox;
    *reinterpret_cast<uint2*>(dv + (size_t)row * stride + c4) = ov;
}

// ---------------- build concatenated bf16 weights [256][768] + bias sums ----
__global__ void build_wcat(const float* __restrict__ Wa,  const float* __restrict__ Wra,
                           const float* __restrict__ Wrb, const float* __restrict__ Wb,
                           const float* __restrict__ ba,  const float* __restrict__ bb,
                           unsigned short* __restrict__ wout, float* __restrict__ bsum) {
    int i = blockIdx.x * blockDim.x + threadIdx.x;
    if (i >= D * D) return;
    int n = i >> 8, k = i & 255;
    wout[(size_t)n * KCAT + k]        = f2bf(Wa[i]);
    wout[(size_t)n * KCAT + 256 + k]  = f2bf(Wra[i] + Wrb[i]);
    wout[(size_t)n * KCAT + 512 + k]  = f2bf(Wb[i]);
    if (i < D) bsum[i] = ba[i] + bb[i];
}

// ---------------- fine counts: LDS-hist for cells, global atomics for genes -
static constexpr int CE_CHUNK = 8192;
__global__ __launch_bounds__(256) void count_edges(const int* __restrict__ dst_g2c,
                                                   const int* __restrict__ dst_c2g,
                                                   int* __restrict__ cnt_c,
                                                   int* __restrict__ cnt_g) {
    __shared__ int h[NC];
    for (int i = threadIdx.x; i < NC; i += 256) h[i] = 0;
    __syncthreads();
    int base = blockIdx.x * CE_CHUNK;
#pragma unroll 4
    for (int t = 0; t < CE_CHUNK / 256; ++t) {
        int e = base + t * 256 + threadIdx.x;
        if (e < NE) {
            atomicAdd(&h[dst_g2c[e]], 1);
            atomicAdd(&cnt_g[dst_c2g[e]], 1);
        }
    }
    __syncthreads();
    for (int i = threadIdx.x; i < NC; i += 256)
        if (h[i]) atomicAdd(&cnt_c[i], h[i]);
}

static constexpr int SCAN_NB = 256;
static constexpr int SCAN_NT = 256;

__global__ __launch_bounds__(256) void scan_phaseA(const int* __restrict__ cnt, int n,
                                                   int* __restrict__ partials) {
    __shared__ int sd[SCAN_NT];
    int chunk = (n + SCAN_NB - 1) / SCAN_NB;
    int ts = (chunk + SCAN_NT - 1) / SCAN_NT;
    int bstart = blockIdx.x * chunk;
    int bend = bstart + chunk; if (bend > n) bend = n;
    int start = bstart + threadIdx.x * ts;
    int end = start + ts; if (end > bend) end = bend;
    int sum = 0;
    for (int j = start; j < end; ++j) sum += cnt[j];
    sd[threadIdx.x] = sum;
    __syncthreads();
    for (int off = SCAN_NT / 2; off > 0; off >>= 1) {
        if (threadIdx.x < off) sd[threadIdx.x] += sd[threadIdx.x + off];
        __syncthreads();
    }
    if (threadIdx.x == 0) partials[blockIdx.x] = sd[0];
}

__global__ __launch_bounds__(256) void scan_phaseB(const int* __restrict__ partials,
                                                   int* __restrict__ blockoff,
                                                   int* __restrict__ rp, int n) {
    __shared__ int sd[SCAN_NB];
    int t = threadIdx.x;
    int v = partials[t];
    sd[t] = v;
    __syncthreads();
    for (int off = 1; off < SCAN_NB; off <<= 1) {
        int u = (t >= off) ? sd[t - off] : 0;
        __syncthreads();
        sd[t] += u;
        __syncthreads();
    }
    blockoff[t] = sd[t] - v;
    if (t == SCAN_NB - 1) rp[n] = sd[SCAN_NB - 1];
}

__global__ __launch_bounds__(256) void scan_phaseC(const int* __restrict__ cnt, int n,
                                                   const int* __restrict__ blockoff,
                                                   int* __restrict__ rp) {
    __shared__ int sd[SCAN_NT];
    int chunk = (n + SCAN_NB - 1) / SCAN_NB;
    int ts = (chunk + SCAN_NT - 1) / SCAN_NT;
    int bstart = blockIdx.x * chunk;
    int bend = bstart + chunk; if (bend > n) bend = n;
    int start = bstart + threadIdx.x * ts;
    int end = start + ts; if (end > bend) end = bend;
    int sum = 0;
    for (int j = start; j < end; ++j) sum += cnt[j];
    sd[threadIdx.x] = sum;
    __syncthreads();
    for (int off = 1; off < SCAN_NT; off <<= 1) {
        int u = (threadIdx.x >= off) ? sd[threadIdx.x - off] : 0;
        __syncthreads();
        sd[threadIdx.x] += u;
        __syncthreads();
    }
    int run = blockoff[blockIdx.x] + sd[threadIdx.x] - sum;
    for (int j = start; j < end; ++j) { rp[j] = run; run += cnt[j]; }
}

// ---------------- two-level binned CSR fill ---------------------------------
// init 256 coarse cursors from rp
__global__ void init_coarse(const int* __restrict__ rp_c, const int* __restrict__ rp_g,
                            int* __restrict__ cc, int* __restrict__ cg) {
    int t = threadIdx.x;
    int ic = t << 3;  if (ic > NC) ic = NC;
    int ig = t << 9;  if (ig > NG) ig = NG;
    cc[t] = rp_c[ic];
    cg[t] = rp_g[ig];
}

// pass1: scatter edges into 256 coarse buckets; packed x = src | dstlow<<packshift
static constexpr int P1_CHUNK = 8192;
__global__ __launch_bounds__(256) void bucket_pass1(const int* __restrict__ src,
                                                    const int* __restrict__ dst,
                                                    const float* __restrict__ w,
                                                    int shift, int packshift,
                                                    int* __restrict__ coarse_cur,
                                                    int2* __restrict__ out) {
    __shared__ int hist[256], lcur[256], gbase[256];
    int tid = threadIdx.x;
    hist[tid] = 0;
    __syncthreads();
    int base = blockIdx.x * P1_CHUNK;
    int mybin[P1_CHUNK / 256];
#pragma unroll
    for (int t = 0; t < P1_CHUNK / 256; ++t) {
        int e = base + t * 256 + tid;
        if (e < NE) {
            int b = dst[e] >> shift;
            mybin[t] = b;
            atomicAdd(&hist[b], 1);
        } else mybin[t] = -1;
    }
    __syncthreads();
    int v = hist[tid];
    gbase[tid] = v ? atomicAdd(&coarse_cur[tid], v) : 0;
    lcur[tid] = 0;
    __syncthreads();
#pragma unroll
    for (int t = 0; t < P1_CHUNK / 256; ++t) {
        int b = mybin[t];
        if (b < 0) continue;
        int e = base + t * 256 + tid;
        int pos = gbase[b] + atomicAdd(&lcur[b], 1);
        int dl = dst[e] & ((1 << shift) - 1);
        out[pos] = make_int2(src[e] | (dl << packshift), __float_as_int(w[e]));
    }
}

// pass2: fine scatter within each bucket (output region is contiguous -> cache-local)
__global__ __launch_bounds__(256) void bucket_pass2(const int2* __restrict__ staged,
                                                    const int* __restrict__ rp,
                                                    int shift, int packshift, int ndst,
                                                    int2* __restrict__ out) {
    __shared__ int cur[512];
    int b = blockIdx.x;
    int nf = 1 << shift;
    int d0 = b << shift;
    for (int f = threadIdx.x; f < nf; f += 256) {
        int d = d0 + f;
        cur[f] = (d < ndst) ? rp[d] : 0;
    }
    __syncthreads();
    int hi = (b + 1) << shift; if (hi > ndst) hi = ndst;
    int j0 = rp[d0], j1 = rp[hi];
    for (int j = j0 + threadIdx.x; j < j1; j += 256) {
        int2 e = staged[j];
        int f = ((unsigned)e.x) >> packshift;
        int pos = atomicAdd(&cur[f], 1);
        out[pos] = make_int2(e.x & ((1 << packshift) - 1), e.y);
    }
}

// ---------------- gene aggregation: one wave per destination row ------------
__global__ void agg_gene(const int* __restrict__ rp, const int2* __restrict__ eg,
                         const unsigned short* __restrict__ src, long sstride,
                         unsigned short* __restrict__ out, long ostride, int nrows) {
    int wave = (blockIdx.x * blockDim.x + threadIdx.x) >> 6;
    int lane = threadIdx.x & 63;
    if (wave >= nrows) return;
    int j0 = rp[wave], j1 = rp[wave + 1];
    float a0 = 0.f, a1 = 0.f, a2 = 0.f, a3 = 0.f;
    for (int j = j0; j < j1; ++j) {
        int2 e = eg[j];
        float w = __int_as_float(e.y);
        uint2 pk = *reinterpret_cast<const uint2*>(src + (size_t)e.x * sstride + lane * 4);
        a0 += w * bflo(pk.x); a1 += w * bfhi(pk.x);
        a2 += w * bflo(pk.y); a3 += w * bfhi(pk.y);
    }
    uint2 o;
    o.x = (unsigned)f2bf(a0) | ((unsigned)f2bf(a1) << 16);
    o.y = (unsigned)f2bf(a2) | ((unsigned)f2bf(a3) << 16);
    *reinterpret_cast<uint2*>(out + (size_t)wave * ostride + lane * 4) = o;
}

// ---------------- cell aggregation: one block per cell, LDS reduce ----------
__global__ __launch_bounds__(256) void agg_cell(const int* __restrict__ rp,
                                                const int2* __restrict__ ec,
                                                const unsigned short* __restrict__ src, long sstride,
                                                unsigned short* __restrict__ out, long ostride) {
    __shared__ float red[4][D];
    int c = blockIdx.x;
    int wv = threadIdx.x >> 6, ln = threadIdx.x & 63;
    int j0 = rp[c], j1 = rp[c + 1];
    float a0 = 0.f, a1 = 0.f, a2 = 0.f, a3 = 0.f;
    for (int j = j0 + wv; j < j1; j += 4) {
        int2 e = ec[j];
        float w = __int_as_float(e.y);
        uint2 pk = *reinterpret_cast<const uint2*>(src + (size_t)e.x * sstride + ln * 4);
        a0 += w * bflo(pk.x); a1 += w * bfhi(pk.x);
        a2 += w * bflo(pk.y); a3 += w * bfhi(pk.y);
    }
    red[wv][ln * 4 + 0] = a0; red[wv][ln * 4 + 1] = a1;
    red[wv][ln * 4 + 2] = a2; red[wv][ln * 4 + 3] = a3;
    __syncthreads();
    int col = threadIdx.x;
    float s = red[0][col] + red[1][col] + red[2][col] + red[3][col];
    out[(size_t)c * ostride + col] = f2bf(s);
}

// ---------------- m97-style GEMM: relu(A[M,768] @ W[256,768]^T + bias) ------
__global__ __launch_bounds__(256, 2) void gemm_tile(
        const unsigned short* __restrict__ A,    // [M][768]
        const unsigned short* __restrict__ W,    // [256][768]
        const float* __restrict__ bias,          // [256]
        const float* __restrict__ wrow,          // nullable per-row scale for vout
        unsigned short* __restrict__ xout, long xstride,
        unsigned short* __restrict__ vout,       // nullable, same stride
        int M) {
    __shared__ unsigned short As[128 * 64];
    __shared__ unsigned short Bs[128 * 64];
    int tid = threadIdx.x;
    int wv = tid >> 6, ln = tid & 63;
    int lm = ln & 15, lq = ln >> 4;
    int m0 = blockIdx.x * 128;
    int nb = blockIdx.y * 128;
    int m0w = m0 + (wv >> 1) * 64;
    int n0w = nb + (wv & 1) * 64;

    f32x4 acc[4][4];
#pragma unroll
    for (int i = 0; i < 4; ++i)
#pragma unroll
        for (int j = 0; j < 4; ++j) acc[i][j] = f32x4{0.f, 0.f, 0.f, 0.f};

    for (int k0 = 0; k0 < KCAT; k0 += 64) {
#pragma unroll
        for (int t = 0; t < 4; ++t) {
            int ci = t * 256 + tid;
            int r = ci >> 3, s = ci & 7;
            int cg = s ^ (r & 7);
            int row = m0 + r; if (row >= M) row = M - 1;
            async16(A + (size_t)row * KCAT + k0 + cg * 8,
                    (unsigned char*)As + ci * 16);
        }
#pragma unroll
        for (int t = 0; t < 4; ++t) {
            int ci = t * 256 + tid;
            int r = ci >> 3, s = ci & 7;
            int cg = s ^ (r & 7);
            async16(W + (size_t)(nb + r) * KCAT + k0 + cg * 8,
                    (unsigned char*)Bs + ci * 16);
        }
        __syncthreads();
#pragma unroll
        for (int kk = 0; kk < 2; ++kk) {
            bf16x8 a[4], b[4];
#pragma unroll
            for (int i = 0; i < 4; ++i) {
                int r = (wv >> 1) * 64 + i * 16 + lm;
                int c = kk * 4 + lq;
                int s = c ^ (r & 7);
                a[i] = *reinterpret_cast<const bf16x8*>(As + (r * 8 + s) * 8);
            }
#pragma unroll
            for (int j = 0; j < 4; ++j) {
                int r = (wv & 1) * 64 + j * 16 + lm;
                int c = kk * 4 + lq;
                int s = c ^ (r & 7);
                b[j] = *reinterpret_cast<const bf16x8*>(Bs + (r * 8 + s) * 8);
            }
#pragma unroll
            for (int i = 0; i < 4; ++i)
#pragma unroll
                for (int j = 0; j < 4; ++j)
                    acc[i][j] = __builtin_amdgcn_mfma_f32_16x16x32_bf16(a[i], b[j], acc[i][j], 0, 0, 0);
        }
        __syncthreads();
    }

#pragma unroll
    for (int i = 0; i < 4; ++i) {
#pragma unroll
        for (int r4 = 0; r4 < 4; ++r4) {
            int rr = m0w + i * 16 + lq * 4 + r4;
            if (rr >= M) continue;
            float wr = wrow ? wrow[rr] : 0.f;
#pragma unroll
            for (int j = 0; j < 4; ++j) {
                int col = n0w + j * 16 + lm;
                float v = acc[i][j][r4] + bias[col];
                v = v > 0.f ? v : 0.f;
                xout[(size_t)rr * xstride + col] = f2bf(v);
                if (vout) vout[(size_t)rr * xstride + col] = f2bf(v * wr);
            }
        }
    }
}

// ---------------- final projection: out = xc2 @ Wout^T + bout (fp32) --------
__global__ void out_kernel(const unsigned short* __restrict__ xc, const float* __restrict__ Wout,
                           const float* __restrict__ bout, float* __restrict__ out) {
    __shared__ float srow[4][D];
    int r = threadIdx.x >> 6;
    int o = threadIdx.x & 63;
    int c = blockIdx.x * 4 + r;
    for (int t = threadIdx.x; t < 4 * D; t += 256) {
        int rr = blockIdx.x * 4 + (t >> 8);
        unsigned short h = xc[(size_t)rr * D + (t & 255)];
        srow[t >> 8][t & 255] = __uint_as_float(((unsigned)h) << 16);
    }
    __syncthreads();
    float s = 0.f;
    const float* wo = Wout + o * D;
    for (int k = 0; k < D; ++k) s += srow[r][k] * wo[k];
    out[(size_t)c * NOUTD + o] = s + bout[o];
}

// ---------------- orchestration ---------------------------------------------
extern "C" void kernel_launch(void* const* d_in, const int* in_sizes, int n_in,
                              void* d_out, int out_size, void* d_ws, size_t ws_size,
                              hipStream_t stream) {
    const float* x_gene = (const float*)d_in[0];
    const float* x_cell = (const float*)d_in[1];
    const int*   src_g2c = (const int*)d_in[2];
    const int*   dst_g2c = (const int*)d_in[3];
    const int*   src_c2g = (const int*)d_in[4];
    const int*   dst_c2g = (const int*)d_in[5];
    const float* w_g2c = (const float*)d_in[8];
    const float* w_c2g = (const float*)d_in[9];
    const float* w_gg  = (const float*)d_in[10];
    const float* w_cc  = (const float*)d_in[11];
    const float* Wrel  = (const float*)d_in[12];
    const float* brel  = (const float*)d_in[13];
    const float* Wroot = (const float*)d_in[14];
    const float* Wout  = (const float*)d_in[15];
    const float* bout  = (const float*)d_in[16];
    float* out = (float*)d_out;

    char* p = (char*)d_ws;
    auto alloc = [&](size_t bytes) -> char* {
        char* r = p;
        p += (bytes + 255) & ~(size_t)255;
        return r;
    };

    unsigned short* Acat_g  = (unsigned short*)alloc((size_t)NG * KCAT * 2);
    unsigned short* xg1     = (unsigned short*)alloc((size_t)NG * D * 2);
    unsigned short* Acat_c0 = (unsigned short*)alloc((size_t)NC * KCAT * 2);
    unsigned short* Acat_c1 = (unsigned short*)alloc((size_t)NC * KCAT * 2);
    unsigned short* xc2     = (unsigned short*)alloc((size_t)NC * D * 2);
    int* rp_g  = (int*)alloc((NG + 1) * 4);
    int* cnt_g = (int*)alloc(NG * 4);
    int* rp_c  = (int*)alloc((NC + 1) * 4);
    int* cnt_c = (int*)alloc(NC * 4);
    int2* ec = (int2*)alloc((size_t)NE * 8);       // g2c edges grouped by cell
    int2* eg = (int2*)alloc((size_t)NE * 8);       // c2g edges grouped by gene
    int2* st_c = (int2*)alloc((size_t)NE * 8);     // coarse-bucketed staging
    int2* st_g = (int2*)alloc((size_t)NE * 8);
    int* ccur_c = (int*)alloc(256 * 4);
    int* ccur_g = (int*)alloc(256 * 4);
    unsigned short* Wg0 = (unsigned short*)alloc((size_t)D * KCAT * 2);
    unsigned short* Wc0 = (unsigned short*)alloc((size_t)D * KCAT * 2);
    unsigned short* Wc1 = (unsigned short*)alloc((size_t)D * KCAT * 2);
    float* bg0 = (float*)alloc(D * 4);
    float* bc0 = (float*)alloc(D * 4);
    float* bc1 = (float*)alloc(D * 4);
    int* part_g = (int*)alloc(SCAN_NB * 4);
    int* boff_g = (int*)alloc(SCAN_NB * 4);
    int* part_c = (int*)alloc(SCAN_NB * 4);
    int* boff_c = (int*)alloc(SCAN_NB * 4);

    hipMemsetAsync(cnt_g, 0, NG * 4, stream);
    hipMemsetAsync(cnt_c, 0, NC * 4, stream);

    prep_x<<<(NG * 64 + 255) / 256, 256, 0, stream>>>(x_gene, w_gg, Acat_g + 256, Acat_g + 512, KCAT, NG);
    prep_x<<<(NC * 64 + 255) / 256, 256, 0, stream>>>(x_cell, w_cc, Acat_c0 + 256, Acat_c0 + 512, KCAT, NC);

    const int WW = D * D;
    build_wcat<<<(WW + 255) / 256, 256, 0, stream>>>(
        Wrel + 1 * WW, Wroot + 1 * WW, Wroot + 2 * WW, Wrel + 2 * WW,
        brel + 1 * D, brel + 2 * D, Wg0, bg0);
    build_wcat<<<(WW + 255) / 256, 256, 0, stream>>>(
        Wrel + 0 * WW, Wroot + 0 * WW, Wroot + 3 * WW, Wrel + 3 * WW,
        brel + 0 * D, brel + 3 * D, Wc0, bc0);
    build_wcat<<<(WW + 255) / 256, 256, 0, stream>>>(
        Wrel + 4 * WW, Wroot + 4 * WW, Wroot + 7 * WW, Wrel + 7 * WW,
        brel + 4 * D, brel + 7 * D, Wc1, bc1);

    // ---- CSR build: counts -> scans -> two-level binned scatter ----
    count_edges<<<(NE + CE_CHUNK - 1) / CE_CHUNK, 256, 0, stream>>>(dst_g2c, dst_c2g, cnt_c, cnt_g);
    scan_phaseA<<<SCAN_NB, SCAN_NT, 0, stream>>>(cnt_g, NG, part_g);
    scan_phaseA<<<SCAN_NB, SCAN_NT, 0, stream>>>(cnt_c, NC, part_c);
    scan_phaseB<<<1, SCAN_NB, 0, stream>>>(part_g, boff_g, rp_g, NG);
    scan_phaseB<<<1, SCAN_NB, 0, stream>>>(part_c, boff_c, rp_c, NC);
    scan_phaseC<<<SCAN_NB, SCAN_NT, 0, stream>>>(cnt_g, NG, boff_g, rp_g);
    scan_phaseC<<<SCAN_NB, SCAN_NT, 0, stream>>>(cnt_c, NC, boff_c, rp_c);
    init_coarse<<<1, 256, 0, stream>>>(rp_c, rp_g, ccur_c, ccur_g);
    const int P1B = (NE + P1_CHUNK - 1) / P1_CHUNK;
    bucket_pass1<<<P1B, 256, 0, stream>>>(src_g2c, dst_g2c, w_g2c, 3, 17, ccur_c, st_c);
    bucket_pass1<<<P1B, 256, 0, stream>>>(src_c2g, dst_c2g, w_c2g, 9, 11, ccur_g, st_g);
    bucket_pass2<<<NC / 8, 256, 0, stream>>>(st_c, rp_c, 3, 17, NC, ec);
    bucket_pass2<<<(NG + 511) / 512, 256, 0, stream>>>(st_g, rp_g, 9, 11, NG, eg);

    // ---- Layer 0 aggregations ----
    agg_cell<<<NC, 256, 0, stream>>>(rp_c, ec, Acat_g + 256, KCAT, Acat_c0, KCAT);
    agg_gene<<<(NG + 3) / 4, 256, 0, stream>>>(rp_g, eg, Acat_c0 + 256, KCAT, Acat_g, KCAT, NG);

    // ---- Layer 0 updates ----
    gemm_tile<<<dim3((NC + 127) / 128, 2), 256, 0, stream>>>(
        Acat_c0, Wc0, bc0, w_cc, Acat_c1 + 256, KCAT, Acat_c1 + 512, NC);
    gemm_tile<<<dim3((NG + 127) / 128, 2), 256, 0, stream>>>(
        Acat_g, Wg0, bg0, nullptr, xg1, D, nullptr, NG);

    // ---- Layer 1 (cells only) ----
    agg_cell<<<NC, 256, 0, stream>>>(rp_c, ec, xg1, D, Acat_c1, KCAT);
    gemm_tile<<<dim3((NC + 127) / 128, 2), 256, 0, stream>>>(
        Acat_c1, Wc1, bc1, nullptr, xc2, D, nullptr, NC);

    // ---- output projection ----
    out_kernel<<<NC / 4, 256, 0, stream>>>(xc2, Wout, bout, out);
}

// Round 5
// 700.505 us; speedup vs baseline: 2.0163x; 1.0963x over previous
//
#include <hip/hip_runtime.h>

// Problem constants
static constexpr int NG   = 100000;
static constexpr int NC   = 2000;
static constexpr int D    = 256;
static constexpr int NE   = 1000000;
static constexpr int NOUTD= 64;
static constexpr int KCAT = 768;          // concatenated K: [agg | x | v]

typedef __bf16 bf16x8 __attribute__((ext_vector_type(8)));
typedef float  f32x4  __attribute__((ext_vector_type(4)));

__device__ __forceinline__ unsigned short f2bf(float f) {
    unsigned u = __float_as_uint(f);
    u += 0x7fffu + ((u >> 16) & 1u);   // RNE
    return (unsigned short)(u >> 16);
}
__device__ __forceinline__ float bflo(unsigned x) { return __uint_as_float((x & 0xffffu) << 16); }
__device__ __forceinline__ float bfhi(unsigned x) { return __uint_as_float(x & 0xffff0000u); }

__device__ __forceinline__ void async16(const void* g, void* l) {
    __builtin_amdgcn_global_load_lds(
        (const __attribute__((address_space(1))) void*)g,
        (__attribute__((address_space(3))) void*)l, 16, 0, 0);
}

// ---------------- prep: f32 -> bf16 into Acat cols [256..512) and [512..768)
__global__ void prep_x(const float* __restrict__ x, const float* __restrict__ w,
                       unsigned short* __restrict__ dx, unsigned short* __restrict__ dv,
                       long stride, int rows) {
    int i = blockIdx.x * blockDim.x + threadIdx.x;   // one per 4 elements
    if (i >= rows * (D / 4)) return;
    int row = i >> 6, c4 = (i & 63) * 4;
    float4 xv = *reinterpret_cast<const float4*>(x + (size_t)row * D + c4);
    float wv = w[row];
    uint2 ox, ov;
    ox.x = (unsigned)f2bf(xv.x) | ((unsigned)f2bf(xv.y) << 16);
    ox.y = (unsigned)f2bf(xv.z) | ((unsigned)f2bf(xv.w) << 16);
    ov.x = (unsigned)f2bf(xv.x * wv) | ((unsigned)f2bf(xv.y * wv) << 16);
    ov.y = (unsigned)f2bf(xv.z * wv) | ((unsigned)f2bf(xv.w * wv) << 16);
    *reinterpret_cast<uint2*>(dx + (size_t)row * stride + c4) = ox;
    *reinterpret_cast<uint2*>(dv + (size_t)row * stride + c4) = ov;
}

// ---------------- build concatenated bf16 weights [256][768] + bias sums ----
__global__ void build_wcat(const float* __restrict__ Wa,  const float* __restrict__ Wra,
                           const float* __restrict__ Wrb, const float* __restrict__ Wb,
                           const float* __restrict__ ba,  const float* __restrict__ bb,
                           unsigned short* __restrict__ wout, float* __restrict__ bsum) {
    int i = blockIdx.x * blockDim.x + threadIdx.x;
    if (i >= D * D) return;
    int n = i >> 8, k = i & 255;
    wout[(size_t)n * KCAT + k]        = f2bf(Wa[i]);
    wout[(size_t)n * KCAT + 256 + k]  = f2bf(Wra[i] + Wrb[i]);
    wout[(size_t)n * KCAT + 512 + k]  = f2bf(Wb[i]);
    if (i < D) bsum[i] = ba[i] + bb[i];
}

// ---------------- fine counts: LDS-hist for cells, global atomics for genes -
static constexpr int CE_CHUNK = 8192;
__global__ __launch_bounds__(256) void count_edges(const int* __restrict__ dst_g2c,
                                                   const int* __restrict__ dst_c2g,
                                                   int* __restrict__ cnt_c,
                                                   int* __restrict__ cnt_g) {
    __shared__ int h[NC];
    for (int i = threadIdx.x; i < NC; i += 256) h[i] = 0;
    __syncthreads();
    int base = blockIdx.x * CE_CHUNK;
#pragma unroll 4
    for (int t = 0; t < CE_CHUNK / 256; ++t) {
        int e = base + t * 256 + threadIdx.x;
        if (e < NE) {
            atomicAdd(&h[dst_g2c[e]], 1);
            atomicAdd(&cnt_g[dst_c2g[e]], 1);
        }
    }
    __syncthreads();
    for (int i = threadIdx.x; i < NC; i += 256)
        if (h[i]) atomicAdd(&cnt_c[i], h[i]);
}

static constexpr int SCAN_NB = 256;
static constexpr int SCAN_NT = 256;

// fused g+c scans: blocks [0,256) handle (cntA,nA), [256,512) handle (cntB,nB)
__global__ __launch_bounds__(256) void scan_phaseA(const int* __restrict__ cntA, int nA,
                                                   int* __restrict__ partA,
                                                   const int* __restrict__ cntB, int nB,
                                                   int* __restrict__ partB) {
    __shared__ int sd[SCAN_NT];
    const int* cnt; int n; int* partials; int b;
    if (blockIdx.x < SCAN_NB) { cnt = cntA; n = nA; partials = partA; b = blockIdx.x; }
    else { cnt = cntB; n = nB; partials = partB; b = blockIdx.x - SCAN_NB; }
    int chunk = (n + SCAN_NB - 1) / SCAN_NB;
    int ts = (chunk + SCAN_NT - 1) / SCAN_NT;
    int bstart = b * chunk;
    int bend = bstart + chunk; if (bend > n) bend = n;
    int start = bstart + threadIdx.x * ts;
    int end = start + ts; if (end > bend) end = bend;
    int sum = 0;
    for (int j = start; j < end; ++j) sum += cnt[j];
    sd[threadIdx.x] = sum;
    __syncthreads();
    for (int off = SCAN_NT / 2; off > 0; off >>= 1) {
        if (threadIdx.x < off) sd[threadIdx.x] += sd[threadIdx.x + off];
        __syncthreads();
    }
    if (threadIdx.x == 0) partials[b] = sd[0];
}

__global__ __launch_bounds__(256) void scan_phaseB(const int* __restrict__ partA,
                                                   int* __restrict__ boffA,
                                                   int* __restrict__ rpA, int nA,
                                                   const int* __restrict__ partB,
                                                   int* __restrict__ boffB,
                                                   int* __restrict__ rpB, int nB) {
    __shared__ int sd[SCAN_NB];
    const int* partials; int* blockoff; int* rp; int n;
    if (blockIdx.x == 0) { partials = partA; blockoff = boffA; rp = rpA; n = nA; }
    else { partials = partB; blockoff = boffB; rp = rpB; n = nB; }
    int t = threadIdx.x;
    int v = partials[t];
    sd[t] = v;
    __syncthreads();
    for (int off = 1; off < SCAN_NB; off <<= 1) {
        int u = (t >= off) ? sd[t - off] : 0;
        __syncthreads();
        sd[t] += u;
        __syncthreads();
    }
    blockoff[t] = sd[t] - v;
    if (t == SCAN_NB - 1) rp[n] = sd[SCAN_NB - 1];
}

__global__ __launch_bounds__(256) void scan_phaseC(const int* __restrict__ cntA, int nA,
                                                   const int* __restrict__ boffA,
                                                   int* __restrict__ rpA,
                                                   const int* __restrict__ cntB, int nB,
                                                   const int* __restrict__ boffB,
                                                   int* __restrict__ rpB) {
    __shared__ int sd[SCAN_NT];
    const int* cnt; int n; const int* blockoff; int* rp; int b;
    if (blockIdx.x < SCAN_NB) { cnt = cntA; n = nA; blockoff = boffA; rp = rpA; b = blockIdx.x; }
    else { cnt = cntB; n = nB; blockoff = boffB; rp = rpB; b = blockIdx.x - SCAN_NB; }
    int chunk = (n + SCAN_NB - 1) / SCAN_NB;
    int ts = (chunk + SCAN_NT - 1) / SCAN_NT;
    int bstart = b * chunk;
    int bend = bstart + chunk; if (bend > n) bend = n;
    int start = bstart + threadIdx.x * ts;
    int end = start + ts; if (end > bend) end = bend;
    int sum = 0;
    for (int j = start; j < end; ++j) sum += cnt[j];
    sd[threadIdx.x] = sum;
    __syncthreads();
    for (int off = 1; off < SCAN_NT; off <<= 1) {
        int u = (threadIdx.x >= off) ? sd[threadIdx.x - off] : 0;
        __syncthreads();
        sd[threadIdx.x] += u;
        __syncthreads();
    }
    int run = blockoff[b] + sd[threadIdx.x] - sum;
    for (int j = start; j < end; ++j) { rp[j] = run; run += cnt[j]; }
}

// ---------------- two-level binned CSR fill ---------------------------------
__global__ void init_coarse(const int* __restrict__ rp_c, const int* __restrict__ rp_g,
                            int* __restrict__ cc, int* __restrict__ cg) {
    int t = threadIdx.x;
    int ic = t << 3;  if (ic > NC) ic = NC;
    int ig = t << 9;  if (ig > NG) ig = NG;
    cc[t] = rp_c[ic];
    cg[t] = rp_g[ig];
}

// pass1 (fused c/g via blockIdx.y): scatter edges into 256 coarse buckets
static constexpr int P1_CHUNK = 8192;
__global__ __launch_bounds__(256) void bucket_pass1(
        const int* __restrict__ srcA, const int* __restrict__ dstA, const float* __restrict__ wA,
        int* __restrict__ curA, int2* __restrict__ outA,
        const int* __restrict__ srcB, const int* __restrict__ dstB, const float* __restrict__ wB,
        int* __restrict__ curB, int2* __restrict__ outB) {
    __shared__ int hist[256], lcur[256], gbase[256];
    const int* src; const int* dst; const float* w; int* coarse_cur; int2* out;
    int shift, packshift;
    if (blockIdx.y == 0) { src = srcA; dst = dstA; w = wA; coarse_cur = curA; out = outA; shift = 3; packshift = 17; }
    else { src = srcB; dst = dstB; w = wB; coarse_cur = curB; out = outB; shift = 9; packshift = 11; }
    int tid = threadIdx.x;
    hist[tid] = 0;
    __syncthreads();
    int base = blockIdx.x * P1_CHUNK;
    int mybin[P1_CHUNK / 256];
#pragma unroll
    for (int t = 0; t < P1_CHUNK / 256; ++t) {
        int e = base + t * 256 + tid;
        if (e < NE) {
            int b = dst[e] >> shift;
            mybin[t] = b;
            atomicAdd(&hist[b], 1);
        } else mybin[t] = -1;
    }
    __syncthreads();
    int v = hist[tid];
    gbase[tid] = v ? atomicAdd(&coarse_cur[tid], v) : 0;
    lcur[tid] = 0;
    __syncthreads();
#pragma unroll
    for (int t = 0; t < P1_CHUNK / 256; ++t) {
        int b = mybin[t];
        if (b < 0) continue;
        int e = base + t * 256 + tid;
        int pos = gbase[b] + atomicAdd(&lcur[b], 1);
        int dl = dst[e] & ((1 << shift) - 1);
        out[pos] = make_int2(src[e] | (dl << packshift), __float_as_int(w[e]));
    }
}

// pass2 (fused): fine scatter within each bucket; cells = blocks [0,250), genes after
static constexpr int P2_CBLK = NC / 8;                 // 250
static constexpr int P2_GBLK = (NG + 511) / 512;       // 196
__global__ __launch_bounds__(256) void bucket_pass2(
        const int2* __restrict__ stC, const int* __restrict__ rpC, int2* __restrict__ outC,
        const int2* __restrict__ stG, const int* __restrict__ rpG, int2* __restrict__ outG) {
    __shared__ int cur[512];
    const int2* staged; const int* rp; int2* out; int shift, packshift, ndst, b;
    if (blockIdx.x < P2_CBLK) { staged = stC; rp = rpC; out = outC; shift = 3; packshift = 17; ndst = NC; b = blockIdx.x; }
    else { staged = stG; rp = rpG; out = outG; shift = 9; packshift = 11; ndst = NG; b = blockIdx.x - P2_CBLK; }
    int nf = 1 << shift;
    int d0 = b << shift;
    for (int f = threadIdx.x; f < nf; f += 256) {
        int d = d0 + f;
        cur[f] = (d < ndst) ? rp[d] : 0;
    }
    __syncthreads();
    int hi = (b + 1) << shift; if (hi > ndst) hi = ndst;
    int j0 = rp[d0], j1 = rp[hi];
    for (int j = j0 + threadIdx.x; j < j1; j += 256) {
        int2 e = staged[j];
        int f = ((unsigned)e.x) >> packshift;
        int pos = atomicAdd(&cur[f], 1);
        out[pos] = make_int2(e.x & ((1 << packshift) - 1), e.y);
    }
}

// ---------------- per-cell sort of edge segments by src gene ----------------
// Sorted lists make all 2000 agg_cell blocks sweep the gene array in
// near-lockstep (degree ~500 +/- 22), turning random gathers into a
// window-coherent sweep that L2/L3 can serve. Sum is order-invariant.
__global__ __launch_bounds__(256) void sort_cell_edges(const int* __restrict__ rp,
                                                       int2* __restrict__ ec) {
    __shared__ int2 s[1024];
    int c = blockIdx.x;
    int j0 = rp[c], j1 = rp[c + 1];
    int n = j1 - j0;
    if (n <= 1 || n > 1024) return;   // skip = perf-only fallback
    for (int i = threadIdx.x; i < 1024; i += 256)
        s[i] = (i < n) ? ec[j0 + i] : make_int2(0x7fffffff, 0);
    __syncthreads();
    for (int k = 2; k <= 1024; k <<= 1) {
        for (int jj = k >> 1; jj > 0; jj >>= 1) {
#pragma unroll
            for (int t = 0; t < 4; ++t) {
                int i = threadIdx.x + t * 256;
                int ixj = i ^ jj;
                if (ixj > i) {
                    int2 a = s[i], b = s[ixj];
                    bool up = ((i & k) == 0);
                    if ((a.x > b.x) == up) { s[i] = b; s[ixj] = a; }
                }
            }
            __syncthreads();
        }
    }
    for (int i = threadIdx.x; i < n; i += 256) ec[j0 + i] = s[i];
}

// ---------------- gene aggregation: one wave per destination row ------------
__global__ void agg_gene(const int* __restrict__ rp, const int2* __restrict__ eg,
                         const unsigned short* __restrict__ src, long sstride,
                         unsigned short* __restrict__ out, long ostride, int nrows) {
    int wave = (blockIdx.x * blockDim.x + threadIdx.x) >> 6;
    int lane = threadIdx.x & 63;
    if (wave >= nrows) return;
    int j0 = rp[wave], j1 = rp[wave + 1];
    float a0 = 0.f, a1 = 0.f, a2 = 0.f, a3 = 0.f;
    int npair = (j1 - j0) & ~1;
    for (int j = j0; j < j0 + npair; j += 2) {
        int2 e1 = eg[j], e2 = eg[j + 1];
        float w1 = __int_as_float(e1.y), w2 = __int_as_float(e2.y);
        uint2 p1 = *reinterpret_cast<const uint2*>(src + (size_t)e1.x * sstride + lane * 4);
        uint2 p2 = *reinterpret_cast<const uint2*>(src + (size_t)e2.x * sstride + lane * 4);
        a0 += w1 * bflo(p1.x) + w2 * bflo(p2.x);
        a1 += w1 * bfhi(p1.x) + w2 * bfhi(p2.x);
        a2 += w1 * bflo(p1.y) + w2 * bflo(p2.y);
        a3 += w1 * bfhi(p1.y) + w2 * bfhi(p2.y);
    }
    if (npair < j1 - j0) {
        int2 e = eg[j0 + npair];
        float w = __int_as_float(e.y);
        uint2 pk = *reinterpret_cast<const uint2*>(src + (size_t)e.x * sstride + lane * 4);
        a0 += w * bflo(pk.x); a1 += w * bfhi(pk.x);
        a2 += w * bflo(pk.y); a3 += w * bfhi(pk.y);
    }
    uint2 o;
    o.x = (unsigned)f2bf(a0) | ((unsigned)f2bf(a1) << 16);
    o.y = (unsigned)f2bf(a2) | ((unsigned)f2bf(a3) << 16);
    *reinterpret_cast<uint2*>(out + (size_t)wave * ostride + lane * 4) = o;
}

// ---------------- cell aggregation: one block per cell, LDS reduce ----------
__global__ __launch_bounds__(256) void agg_cell(const int* __restrict__ rp,
                                                const int2* __restrict__ ec,
                                                const unsigned short* __restrict__ src, long sstride,
                                                unsigned short* __restrict__ out, long ostride) {
    __shared__ float red[4][D];
    int c = blockIdx.x;
    int wv = threadIdx.x >> 6, ln = threadIdx.x & 63;
    int j0 = rp[c], j1 = rp[c + 1];
    float a0 = 0.f, a1 = 0.f, a2 = 0.f, a3 = 0.f;
    int npair = (j1 - j0) & ~7;        // chunks of 8 = 4 waves x 2 edges
    for (int j = j0 + wv * 2; j < j0 + npair; j += 8) {
        int2 e1 = ec[j], e2 = ec[j + 1];
        float w1 = __int_as_float(e1.y), w2 = __int_as_float(e2.y);
        uint2 p1 = *reinterpret_cast<const uint2*>(src + (size_t)e1.x * sstride + ln * 4);
        uint2 p2 = *reinterpret_cast<const uint2*>(src + (size_t)e2.x * sstride + ln * 4);
        a0 += w1 * bflo(p1.x) + w2 * bflo(p2.x);
        a1 += w1 * bfhi(p1.x) + w2 * bfhi(p2.x);
        a2 += w1 * bflo(p1.y) + w2 * bflo(p2.y);
        a3 += w1 * bfhi(p1.y) + w2 * bfhi(p2.y);
    }
    for (int j = j0 + npair + wv; j < j1; j += 4) {
        int2 e = ec[j];
        float w = __int_as_float(e.y);
        uint2 pk = *reinterpret_cast<const uint2*>(src + (size_t)e.x * sstride + ln * 4);
        a0 += w * bflo(pk.x); a1 += w * bfhi(pk.x);
        a2 += w * bflo(pk.y); a3 += w * bfhi(pk.y);
    }
    red[wv][ln * 4 + 0] = a0; red[wv][ln * 4 + 1] = a1;
    red[wv][ln * 4 + 2] = a2; red[wv][ln * 4 + 3] = a3;
    __syncthreads();
    int col = threadIdx.x;
    float s = red[0][col] + red[1][col] + red[2][col] + red[3][col];
    out[(size_t)c * ostride + col] = f2bf(s);
}

// ---------------- m97-style GEMM: relu(A[M,768] @ W[256,768]^T + bias) ------
__global__ __launch_bounds__(256, 2) void gemm_tile(
        const unsigned short* __restrict__ A,    // [M][768]
        const unsigned short* __restrict__ W,    // [256][768]
        const float* __restrict__ bias,          // [256]
        const float* __restrict__ wrow,          // nullable per-row scale for vout
        unsigned short* __restrict__ xout, long xstride,
        unsigned short* __restrict__ vout,       // nullable, same stride
        int M) {
    __shared__ unsigned short As[128 * 64];
    __shared__ unsigned short Bs[128 * 64];
    int tid = threadIdx.x;
    int wv = tid >> 6, ln = tid & 63;
    int lm = ln & 15, lq = ln >> 4;
    int m0 = blockIdx.x * 128;
    int nb = blockIdx.y * 128;
    int m0w = m0 + (wv >> 1) * 64;
    int n0w = nb + (wv & 1) * 64;

    f32x4 acc[4][4];
#pragma unroll
    for (int i = 0; i < 4; ++i)
#pragma unroll
        for (int j = 0; j < 4; ++j) acc[i][j] = f32x4{0.f, 0.f, 0.f, 0.f};

    for (int k0 = 0; k0 < KCAT; k0 += 64) {
#pragma unroll
        for (int t = 0; t < 4; ++t) {
            int ci = t * 256 + tid;
            int r = ci >> 3, s = ci & 7;
            int cg = s ^ (r & 7);
            int row = m0 + r; if (row >= M) row = M - 1;
            async16(A + (size_t)row * KCAT + k0 + cg * 8,
                    (unsigned char*)As + ci * 16);
        }
#pragma unroll
        for (int t = 0; t < 4; ++t) {
            int ci = t * 256 + tid;
            int r = ci >> 3, s = ci & 7;
            int cg = s ^ (r & 7);
            async16(W + (size_t)(nb + r) * KCAT + k0 + cg * 8,
                    (unsigned char*)Bs + ci * 16);
        }
        __syncthreads();
#pragma unroll
        for (int kk = 0; kk < 2; ++kk) {
            bf16x8 a[4], b[4];
#pragma unroll
            for (int i = 0; i < 4; ++i) {
                int r = (wv >> 1) * 64 + i * 16 + lm;
                int c = kk * 4 + lq;
                int s = c ^ (r & 7);
                a[i] = *reinterpret_cast<const bf16x8*>(As + (r * 8 + s) * 8);
            }
#pragma unroll
            for (int j = 0; j < 4; ++j) {
                int r = (wv & 1) * 64 + j * 16 + lm;
                int c = kk * 4 + lq;
                int s = c ^ (r & 7);
                b[j] = *reinterpret_cast<const bf16x8*>(Bs + (r * 8 + s) * 8);
            }
#pragma unroll
            for (int i = 0; i < 4; ++i)
#pragma unroll
                for (int j = 0; j < 4; ++j)
                    acc[i][j] = __builtin_amdgcn_mfma_f32_16x16x32_bf16(a[i], b[j], acc[i][j], 0, 0, 0);
        }
        __syncthreads();
    }

#pragma unroll
    for (int i = 0; i < 4; ++i) {
#pragma unroll
        for (int r4 = 0; r4 < 4; ++r4) {
            int rr = m0w + i * 16 + lq * 4 + r4;
            if (rr >= M) continue;
            float wr = wrow ? wrow[rr] : 0.f;
#pragma unroll
            for (int j = 0; j < 4; ++j) {
                int col = n0w + j * 16 + lm;
                float v = acc[i][j][r4] + bias[col];
                v = v > 0.f ? v : 0.f;
                xout[(size_t)rr * xstride + col] = f2bf(v);
                if (vout) vout[(size_t)rr * xstride + col] = f2bf(v * wr);
            }
        }
    }
}

// ---------------- final projection: out = xc2 @ Wout^T + bout (fp32) --------
__global__ void out_kernel(const unsigned short* __restrict__ xc, const float* __restrict__ Wout,
                           const float* __restrict__ bout, float* __restrict__ out) {
    __shared__ float srow[4][D];
    int r = threadIdx.x >> 6;
    int o = threadIdx.x & 63;
    int c = blockIdx.x * 4 + r;
    for (int t = threadIdx.x; t < 4 * D; t += 256) {
        int rr = blockIdx.x * 4 + (t >> 8);
        unsigned short h = xc[(size_t)rr * D + (t & 255)];
        srow[t >> 8][t & 255] = __uint_as_float(((unsigned)h) << 16);
    }
    __syncthreads();
    float s = 0.f;
    const float* wo = Wout + o * D;
    for (int k = 0; k < D; ++k) s += srow[r][k] * wo[k];
    out[(size_t)c * NOUTD + o] = s + bout[o];
}

// ---------------- orchestration ---------------------------------------------
extern "C" void kernel_launch(void* const* d_in, const int* in_sizes, int n_in,
                              void* d_out, int out_size, void* d_ws, size_t ws_size,
                              hipStream_t stream) {
    const float* x_gene = (const float*)d_in[0];
    const float* x_cell = (const float*)d_in[1];
    const int*   src_g2c = (const int*)d_in[2];
    const int*   dst_g2c = (const int*)d_in[3];
    const int*   src_c2g = (const int*)d_in[4];
    const int*   dst_c2g = (const int*)d_in[5];
    const float* w_g2c = (const float*)d_in[8];
    const float* w_c2g = (const float*)d_in[9];
    const float* w_gg  = (const float*)d_in[10];
    const float* w_cc  = (const float*)d_in[11];
    const float* Wrel  = (const float*)d_in[12];
    const float* brel  = (const float*)d_in[13];
    const float* Wroot = (const float*)d_in[14];
    const float* Wout  = (const float*)d_in[15];
    const float* bout  = (const float*)d_in[16];
    float* out = (float*)d_out;

    char* p = (char*)d_ws;
    auto alloc = [&](size_t bytes) -> char* {
        char* r = p;
        p += (bytes + 255) & ~(size_t)255;
        return r;
    };

    unsigned short* Acat_g  = (unsigned short*)alloc((size_t)NG * KCAT * 2);
    unsigned short* xg1     = (unsigned short*)alloc((size_t)NG * D * 2);
    unsigned short* Acat_c0 = (unsigned short*)alloc((size_t)NC * KCAT * 2);
    unsigned short* Acat_c1 = (unsigned short*)alloc((size_t)NC * KCAT * 2);
    unsigned short* xc2     = (unsigned short*)alloc((size_t)NC * D * 2);
    int* rp_g  = (int*)alloc((NG + 1) * 4);
    int* cnt_g = (int*)alloc(NG * 4);
    int* rp_c  = (int*)alloc((NC + 1) * 4);
    int* cnt_c = (int*)alloc(NC * 4);
    int2* ec = (int2*)alloc((size_t)NE * 8);       // g2c edges grouped by cell
    int2* eg = (int2*)alloc((size_t)NE * 8);       // c2g edges grouped by gene
    int2* st_c = (int2*)alloc((size_t)NE * 8);     // coarse-bucketed staging
    int2* st_g = (int2*)alloc((size_t)NE * 8);
    int* ccur_c = (int*)alloc(256 * 4);
    int* ccur_g = (int*)alloc(256 * 4);
    unsigned short* Wg0 = (unsigned short*)alloc((size_t)D * KCAT * 2);
    unsigned short* Wc0 = (unsigned short*)alloc((size_t)D * KCAT * 2);
    unsigned short* Wc1 = (unsigned short*)alloc((size_t)D * KCAT * 2);
    float* bg0 = (float*)alloc(D * 4);
    float* bc0 = (float*)alloc(D * 4);
    float* bc1 = (float*)alloc(D * 4);
    int* part_g = (int*)alloc(SCAN_NB * 4);
    int* boff_g = (int*)alloc(SCAN_NB * 4);
    int* part_c = (int*)alloc(SCAN_NB * 4);
    int* boff_c = (int*)alloc(SCAN_NB * 4);

    hipMemsetAsync(cnt_g, 0, NG * 4, stream);
    hipMemsetAsync(cnt_c, 0, NC * 4, stream);

    prep_x<<<(NG * 64 + 255) / 256, 256, 0, stream>>>(x_gene, w_gg, Acat_g + 256, Acat_g + 512, KCAT, NG);
    prep_x<<<(NC * 64 + 255) / 256, 256, 0, stream>>>(x_cell, w_cc, Acat_c0 + 256, Acat_c0 + 512, KCAT, NC);

    const int WW = D * D;
    build_wcat<<<(WW + 255) / 256, 256, 0, stream>>>(
        Wrel + 1 * WW, Wroot + 1 * WW, Wroot + 2 * WW, Wrel + 2 * WW,
        brel + 1 * D, brel + 2 * D, Wg0, bg0);
    build_wcat<<<(WW + 255) / 256, 256, 0, stream>>>(
        Wrel + 0 * WW, Wroot + 0 * WW, Wroot + 3 * WW, Wrel + 3 * WW,
        brel + 0 * D, brel + 3 * D, Wc0, bc0);
    build_wcat<<<(WW + 255) / 256, 256, 0, stream>>>(
        Wrel + 4 * WW, Wroot + 4 * WW, Wroot + 7 * WW, Wrel + 7 * WW,
        brel + 4 * D, brel + 7 * D, Wc1, bc1);

    // ---- CSR build ----
    count_edges<<<(NE + CE_CHUNK - 1) / CE_CHUNK, 256, 0, stream>>>(dst_g2c, dst_c2g, cnt_c, cnt_g);
    scan_phaseA<<<2 * SCAN_NB, SCAN_NT, 0, stream>>>(cnt_g, NG, part_g, cnt_c, NC, part_c);
    scan_phaseB<<<2, SCAN_NB, 0, stream>>>(part_g, boff_g, rp_g, NG, part_c, boff_c, rp_c, NC);
    scan_phaseC<<<2 * SCAN_NB, SCAN_NT, 0, stream>>>(cnt_g, NG, boff_g, rp_g, cnt_c, NC, boff_c, rp_c);
    init_coarse<<<1, 256, 0, stream>>>(rp_c, rp_g, ccur_c, ccur_g);
    const int P1B = (NE + P1_CHUNK - 1) / P1_CHUNK;
    bucket_pass1<<<dim3(P1B, 2), 256, 0, stream>>>(
        src_g2c, dst_g2c, w_g2c, ccur_c, st_c,
        src_c2g, dst_c2g, w_c2g, ccur_g, st_g);
    bucket_pass2<<<P2_CBLK + P2_GBLK, 256, 0, stream>>>(st_c, rp_c, ec, st_g, rp_g, eg);
    sort_cell_edges<<<NC, 256, 0, stream>>>(rp_c, ec);

    // ---- Layer 0 aggregations ----
    agg_cell<<<NC, 256, 0, stream>>>(rp_c, ec, Acat_g + 256, KCAT, Acat_c0, KCAT);
    agg_gene<<<(NG + 3) / 4, 256, 0, stream>>>(rp_g, eg, Acat_c0 + 256, KCAT, Acat_g, KCAT, NG);

    // ---- Layer 0 updates ----
    gemm_tile<<<dim3((NC + 127) / 128, 2), 256, 0, stream>>>(
        Acat_c0, Wc0, bc0, w_cc, Acat_c1 + 256, KCAT, Acat_c1 + 512, NC);
    gemm_tile<<<dim3((NG + 127) / 128, 2), 256, 0, stream>>>(
        Acat_g, Wg0, bg0, nullptr, xg1, D, nullptr, NG);

    // ---- Layer 1 (cells only) ----
    agg_cell<<<NC, 256, 0, stream>>>(rp_c, ec, xg1, D, Acat_c1, KCAT);
    gemm_tile<<<dim3((NC + 127) / 128, 2), 256, 0, stream>>>(
        Acat_c1, Wc1, bc1, nullptr, xc2, D, nullptr, NC);

    // ---- output projection ----
    out_kernel<<<NC / 4, 256, 0, stream>>>(xc2, Wout, bout, out);
}